// Round 6
// baseline (457.604 us; speedup 1.0000x reference)
//
#include <hip/hip_runtime.h>
#include <cstdint>
#include <cstddef>

#define BATCH 8
#define SEQ   256
#define DIM   768
#define NSPAN 2020
#define HID   1024
#define NZ    64

typedef unsigned short u16;
typedef unsigned int   u32;
typedef unsigned long long u64;

typedef __bf16 bf16x8 __attribute__((ext_vector_type(8)));
typedef float  f32x4  __attribute__((ext_vector_type(4)));

__device__ __forceinline__ u16 f2bf(float f) {
    union { float f; u32 u; } x; x.f = f;
    u32 r = x.u + 0x7fffu + ((x.u >> 16) & 1u);
    return (u16)(r >> 16);
}
__device__ __forceinline__ float bf2f(u16 b) {
    union { u32 u; float f; } x; x.u = ((u32)b) << 16;
    return x.f;
}
// split v = hi + lo (both bf16); residual v-hi is exact in fp32
__device__ __forceinline__ void splitbf(float v, u16& h, u16& l) {
    h = f2bf(v);
    l = f2bf(v - bf2f(h));
}

// async global->LDS, 16B per lane; LDS dest = wave-uniform base + lane*16;
// global src may be per-lane (row gather OK) [m97/m104]
__device__ __forceinline__ void gld_lds16(const void* g, void* l) {
    __builtin_amdgcn_global_load_lds(
        (const __attribute__((address_space(1))) unsigned int*)g,
        (__attribute__((address_space(3))) unsigned int*)l, 16, 0, 0);
}

// span s -> (start, end, width); spans enumerated width-major: w=1..8, starts 0..L-w
__device__ __forceinline__ void span_decode(int s, int& start, int& end, int& w) {
    int off = 0;
#pragma unroll
    for (int wi = 1; wi <= 8; ++wi) {
        int cnt = SEQ - wi + 1;
        if (s < off + cnt) { w = wi; start = s - off; end = start + wi; return; }
        off += cnt;
    }
    w = 8; start = 0; end = 8;
}

// searchsorted(BUCKET_BINS, d, 'right') - 1
__device__ __forceinline__ int dbucket(int d) {
    int b = 0;
    b += (d >= 1);  b += (d >= 2);  b += (d >= 3);  b += (d >= 4);
    b += (d >= 5);  b += (d >= 7);  b += (d >= 8);  b += (d >= 15);
    b += (d >= 16); b += (d >= 31); b += (d >= 32); b += (d >= 63);
    b += (d >= 64);
    return b;
}

// XCD-aware deswizzle: (linear id) % 8 == by % 8 -> all column-blocks of one
// A-row-tile land on the SAME XCD (id%8 round-robin). sft = log2(nbx).
__device__ __forceinline__ void xcd_map(int L, int sft, int& bx, int& by) {
    int grp = L >> (3 + sft);
    int rem = L & ((1 << (3 + sft)) - 1);
    bx = rem >> 3;
    by = (grp << 3) | (rem & 7);
}

// ---------------------------------------------------------------------------
// k_prep (fused): x hi/lo split | bucket tables | all weight transposes.
// ---------------------------------------------------------------------------
__global__ __launch_bounds__(256) void k_prep(
    const float* __restrict__ x,  u16* __restrict__ xh,   u16* __restrict__ xl,
    const float* __restrict__ wemb, const float* __restrict__ demb,
    const float* __restrict__ bs1, const float* __restrict__ bp1,
    float* __restrict__ wtabS, float* __restrict__ wtabPt,
    float* __restrict__ wtabPo, float* __restrict__ dtab,
    const float* __restrict__ Ws1, u16* __restrict__ W1Th, u16* __restrict__ W1Tl,
    const float* __restrict__ Ws2, u16* __restrict__ W2Th, u16* __restrict__ W2Tl,
    const float* __restrict__ Wp2, u16* __restrict__ Wp2T,
    const float* __restrict__ Wp1, u16* __restrict__ Wp1T4)
{
    __shared__ float tile[32][33];
    const int bid = blockIdx.x, tid = threadIdx.x;
    if (bid < 6144) {
        int i = bid * 256 + tid;         // over 2048*768
        u16 h, l; splitbf(x[i], h, l);
        xh[i] = h; xl[i] = l;
        return;
    }
    if (bid < 6296) {
        int t = bid - 6144;              // 0..151
        int row = t >> 2;                // 0..37
        int h = (t & 3) * 256 + tid;     // 0..1023
        const int wb[8] = {1,2,3,4,5,5,6,7};
        if (row < 8) {
            int bk = wb[row];
            float acc = bs1[h];
            for (int j = 0; j < 25; ++j) acc = fmaf(wemb[bk*25+j], Ws1[(size_t)(1536+j)*HID + h], acc);
            wtabS[row*HID + h] = acc;
        } else if (row < 16) {
            int bk = wb[row-8];
            float acc = 0.f;
            for (int j = 0; j < 25; ++j) acc = fmaf(wemb[bk*25+j], Wp1[(size_t)(1536+j)*HID + h], acc);
            wtabPt[(row-8)*HID + h] = acc;
        } else if (row < 24) {
            int bk = wb[row-16];
            float acc = 0.f;
            for (int j = 0; j < 25; ++j) acc = fmaf(wemb[bk*25+j], Wp1[(size_t)(3097+j)*HID + h], acc);
            wtabPo[(row-16)*HID + h] = acc;
        } else {
            int tt = row - 24;           // 0..13
            float acc = bp1[h];
            for (int j = 0; j < 25; ++j) acc = fmaf(demb[tt*25+j], Wp1[(size_t)(3122+j)*HID + h], acc);
            dtab[tt*HID + h] = acc;
        }
        return;
    }
    // transpose jobs
    const int tb = bid - 6296;           // 0..6655
    const int tr = tid >> 3;             // 0..31
    const int tc4 = (tid & 7) * 4;       // 0,4,..,28
    int job, tk, tn, blk = 0;
    if (tb < 1536)      { job = 0; tk = tb % 24; tn = tb / 24; }
    else if (tb < 2560) { job = 1; int t = tb - 1536; tk = t & 31; tn = t >> 5; }
    else if (tb < 3584) { job = 2; int t = tb - 2560; tk = t & 31; tn = t >> 5; }
    else                { job = 3; int t = tb - 3584; blk = t / 768; int r = t - blk * 768; tk = r % 24; tn = r / 24; }
    const int k0 = tk * 32, n0 = tn * 32;

    int k = k0 + tr;
    float4 v;
    if (job == 0) {
        const float* s = (n0 < 1024) ? (Ws1 + (size_t)k * HID + n0)
                                     : (Ws1 + (size_t)(768 + k) * HID + (n0 - 1024));
        v = *(const float4*)(s + tc4);
    } else if (job == 1) {
        v = *(const float4*)(Ws2 + (size_t)k * HID + n0 + tc4);
    } else if (job == 2) {
        v = *(const float4*)(Wp2 + (size_t)k * HID + n0 + tc4);
    } else {
        const int roff[4] = {0, 768, 1561, 2329};   // (T,p0),(T,p1),(O,p0),(O,p1)
        v = *(const float4*)(Wp1 + (size_t)(roff[blk] + k) * HID + n0 + tc4);
    }
    tile[tr][tc4+0] = v.x; tile[tr][tc4+1] = v.y;
    tile[tr][tc4+2] = v.z; tile[tr][tc4+3] = v.w;
    __syncthreads();

    int nn = n0 + tr;
    float w0 = tile[tc4+0][tr], w1 = tile[tc4+1][tr];
    float w2 = tile[tc4+2][tr], w3 = tile[tc4+3][tr];
    if (job == 0) {
        size_t d = (size_t)nn * 768 + k0 + tc4;
        u16 h0,l0,h1,l1,h2,l2,h3,l3;
        splitbf(w0,h0,l0); splitbf(w1,h1,l1); splitbf(w2,h2,l2); splitbf(w3,h3,l3);
        *(uint2*)(W1Th + d) = make_uint2((u32)h0 | ((u32)h1 << 16), (u32)h2 | ((u32)h3 << 16));
        *(uint2*)(W1Tl + d) = make_uint2((u32)l0 | ((u32)l1 << 16), (u32)l2 | ((u32)l3 << 16));
    } else if (job == 1) {
        size_t d = (size_t)nn * 1024 + k0 + tc4;
        u16 h0,l0,h1,l1,h2,l2,h3,l3;
        splitbf(w0,h0,l0); splitbf(w1,h1,l1); splitbf(w2,h2,l2); splitbf(w3,h3,l3);
        *(uint2*)(W2Th + d) = make_uint2((u32)h0 | ((u32)h1 << 16), (u32)h2 | ((u32)h3 << 16));
        *(uint2*)(W2Tl + d) = make_uint2((u32)l0 | ((u32)l1 << 16), (u32)l2 | ((u32)l3 << 16));
    } else if (job == 2) {
        size_t d = (size_t)nn * 1024 + k0 + tc4;
        *(uint2*)(Wp2T + d) = make_uint2((u32)f2bf(w0) | ((u32)f2bf(w1) << 16),
                                         (u32)f2bf(w2) | ((u32)f2bf(w3) << 16));
    } else {
        size_t d = (size_t)blk * 786432 + (size_t)nn * 768 + k0 + tc4;
        *(uint2*)(Wp1T4 + d) = make_uint2((u32)f2bf(w0) | ((u32)f2bf(w1) << 16),
                                          (u32)f2bf(w2) | ((u32)f2bf(w3) << 16));
    }
}

// ---------------------------------------------------------------------------
// Error-compensated split-bf16 MFMA GEMM: C = AhBh + AlBh + AhBl  (XALL path)
// 128x128 tile, BK=32, dbuf + counted vmcnt(8) (no per-K-step drain).
// 1 wave/SIMD (256 wgs) -- the drain removal is the whole win here.
// ---------------------------------------------------------------------------
__global__ __launch_bounds__(256) void k_gemm3bf(
    const u16* __restrict__ Ah, const u16* __restrict__ Al, int lda,
    const u16* __restrict__ BTh, const u16* __restrict__ BTl, int ldb,
    float* __restrict__ C, int ldc,
    int M, int K, int nby, int sft)
{
    int bx, by;
    xcd_map(blockIdx.x, sft, bx, by);
    if (by >= nby) return;
    __shared__ __align__(16) u16 sm[2 * 16384];        // 64 KiB dbuf
    const int tid = threadIdx.x;
    const int bm = by * 128, bn = bx * 128;
    const int wave = tid >> 6, lane = tid & 63;
    const int wr = wave >> 1, wc = wave & 1;
    const int q = lane >> 4, tl = lane & 15;

    f32x4 zero = {0.f, 0.f, 0.f, 0.f};
    f32x4 acc[4][4];
#pragma unroll
    for (int i = 0; i < 4; ++i)
#pragma unroll
        for (int j = 0; j < 4; ++j) acc[i][j] = zero;

    const int srow = lane >> 2;
    const int scol = (lane & 3) * 8;
    int ra0 = bm + wave * 32 + srow;      if (ra0 >= M) ra0 = M - 1;
    int ra1 = bm + wave * 32 + 16 + srow; if (ra1 >= M) ra1 = M - 1;
    const int rb0 = bn + wave * 32 + srow;
    const int rb1 = bn + wave * 32 + 16 + srow;
    // per-buf offsets: Ah[0) Al[4096) Bh[8192) Bl[12288)
    const u32 oA0 = wave * 1024,          oA1 = oA0 + 512;
    const u32 oL0 = 4096 + wave * 1024,   oL1 = oL0 + 512;
    const u32 oB0 = 8192 + wave * 1024,   oB1 = oB0 + 512;
    const u32 oC0 = 12288 + wave * 1024,  oC1 = oC0 + 512;
    const u16* gA0 = Ah  + (size_t)ra0 * lda + scol;
    const u16* gA1 = Ah  + (size_t)ra1 * lda + scol;
    const u16* gL0 = Al  + (size_t)ra0 * lda + scol;
    const u16* gL1 = Al  + (size_t)ra1 * lda + scol;
    const u16* gB0 = BTh + (size_t)rb0 * ldb + scol;
    const u16* gB1 = BTh + (size_t)rb1 * ldb + scol;
    const u16* gC0 = BTl + (size_t)rb0 * ldb + scol;
    const u16* gC1 = BTl + (size_t)rb1 * ldb + scol;

    // prologue: tile 0 -> buf 0
    gld_lds16(gA0, sm + oA0); gld_lds16(gA1, sm + oA1);
    gld_lds16(gL0, sm + oL0); gld_lds16(gL1, sm + oL1);
    gld_lds16(gB0, sm + oB0); gld_lds16(gB1, sm + oB1);
    gld_lds16(gC0, sm + oC0); gld_lds16(gC1, sm + oC1);
    asm volatile("s_waitcnt vmcnt(0)" ::: "memory");
    asm volatile("s_barrier" ::: "memory");

    const int NT = K >> 5;
    for (int kt = 0; kt < NT; ++kt) {
        const u16* smr = sm + ((kt & 1) ? 16384u : 0u);
        u16*       smw = sm + ((kt & 1) ? 0u : 16384u);
        if (kt < NT - 1) {
            const int k0 = (kt + 1) * 32;
            gld_lds16(gA0 + k0, smw + oA0); gld_lds16(gA1 + k0, smw + oA1);
            gld_lds16(gL0 + k0, smw + oL0); gld_lds16(gL1 + k0, smw + oL1);
            gld_lds16(gB0 + k0, smw + oB0); gld_lds16(gB1 + k0, smw + oB1);
            gld_lds16(gC0 + k0, smw + oC0); gld_lds16(gC1 + k0, smw + oC1);
            asm volatile("s_waitcnt vmcnt(8)" ::: "memory");   // tile kt landed; kt+1 in flight
        } else {
            asm volatile("s_waitcnt vmcnt(0)" ::: "memory");
        }
        asm volatile("s_barrier" ::: "memory");
        bf16x8 ah[4], al[4], bh[4], bl[4];
#pragma unroll
        for (int t = 0; t < 4; ++t) {
            int arow = (wr*64 + t*16 + tl) * 32 + q*8;
            int brow = (wc*64 + t*16 + tl) * 32 + q*8;
            ah[t] = *(const bf16x8*)(smr + arow);
            al[t] = *(const bf16x8*)(smr + 4096 + arow);
            bh[t] = *(const bf16x8*)(smr + 8192 + brow);
            bl[t] = *(const bf16x8*)(smr + 12288 + brow);
        }
#pragma unroll
        for (int ti = 0; ti < 4; ++ti)
#pragma unroll
            for (int tj = 0; tj < 4; ++tj) {
                acc[ti][tj] = __builtin_amdgcn_mfma_f32_16x16x32_bf16(ah[ti], bh[tj], acc[ti][tj], 0, 0, 0);
                acc[ti][tj] = __builtin_amdgcn_mfma_f32_16x16x32_bf16(al[ti], bh[tj], acc[ti][tj], 0, 0, 0);
                acc[ti][tj] = __builtin_amdgcn_mfma_f32_16x16x32_bf16(ah[ti], bl[tj], acc[ti][tj], 0, 0, 0);
            }
        asm volatile("s_barrier" ::: "memory");
    }
    // C/D layout: col = lane&15, row = (lane>>4)*4 + reg  [measured m89/m91]
#pragma unroll
    for (int ti = 0; ti < 4; ++ti) {
#pragma unroll
        for (int tj = 0; tj < 4; ++tj) {
            int gcol = bn + wc*64 + tj*16 + tl;
#pragma unroll
            for (int r = 0; r < 4; ++r) {
                int grow = bm + wr*64 + ti*16 + q*4 + r;
                if (grow >= M) continue;
                C[(size_t)grow * ldc + gcol] = acc[ti][tj][r];
            }
        }
    }
}

#define MFB __builtin_amdgcn_mfma_f32_16x16x32_bf16
#define MFROW(i, A, B) \
    acc[i][0] = MFB(A, B[0], acc[i][0], 0, 0, 0); \
    acc[i][1] = MFB(A, B[1], acc[i][1], 0, 0, 0); \
    acc[i][2] = MFB(A, B[2], acc[i][2], 0, 0, 0); \
    acc[i][3] = MFB(A, B[3], acc[i][3], 0, 0, 0);

// ---------------------------------------------------------------------------
// Span layer-2 GEMM v3.3 (intra-cluster interleave): 256x256 tile, 8 waves,
// BK=32, dbuf, 4 phases/K-tile. Next-phase A ds_reads placed INSIDE the MFMA
// cluster (after first 8 MFMAs, no trailing sched_barrier) so the LDS pipe
// overlaps the matrix pipe within each wave. Ledger {5,6,7,3}, issues 3/2/2/1.
// Phase-3: X-loads mid-cluster (smw valid post vmcnt(3)); B-reload in tail
// (WAR on b-regs). bar2 kept at iteration boundary. 3-pass split-bf16,
// per-acc order hh,lh,hl ascending K (bit-identical). Fused L3 epilogue.
// ---------------------------------------------------------------------------
__global__ __launch_bounds__(512, 2) void k_span_l2(
    const u16* __restrict__ Ah, const u16* __restrict__ Al,
    const u16* __restrict__ BTh, const u16* __restrict__ BTl,
    const float* __restrict__ bs2, const float* __restrict__ Ws3,
    float* __restrict__ part, int M)
{
    __shared__ __align__(16) u16 sm[65536];            // 128 KiB, 2 bufs
    const int tid = threadIdx.x;
    const int swz = (blockIdx.x & 7) * 32 + (blockIdx.x >> 3);   // 256 wgs, 8 XCDs
    const int by = swz >> 2, bx = swz & 3;
    const int bm = by * 256, bn = bx * 256;
    const int wave = tid >> 6, lane = tid & 63;
    const int wm = wave >> 2, wn = wave & 3;           // 2M x 4N waves
    const int tl = lane & 15, q8 = lane >> 4;

    // stage-side: lane -> (subtile row, stored chunk) ; logical chunk via swizzle
    const int sr  = lane >> 2;
    const int scs = lane & 3;
    const int scl = scs ^ ((sr >> 1) & 3);
    // per-wave chunk table: c0..c3 = B (Bh h0, Bh h1, Bl h0, Bl h1; sb=wave),
    // c4+p = A group for phase p (arr=w>>2, half=(w>>1)&1, sb=2p+(w&1))
    const u16* gsrc[8];
    u32 ldst[8];
#pragma unroll
    for (int c = 0; c < 4; ++c) {
        int arr  = 2 + (c >> 1);           // 2=Bh 3=Bl
        int half = c & 1;
        int sb   = wave;
        int row  = bn + half * 128 + sb * 16 + sr;
        const u16* base = (arr == 2) ? BTh : BTl;
        gsrc[c] = base + (size_t)row * HID + scl * 8;
        ldst[c] = arr * 8192 + half * 4096 + sb * 512;
    }
#pragma unroll
    for (int p = 0; p < 4; ++p) {
        int arr  = wave >> 2;              // 0=Ah 1=Al
        int half = (wave >> 1) & 1;
        int sb   = 2 * p + (wave & 1);
        int row  = bm + half * 128 + sb * 16 + sr;
        if (row >= M) row = M - 1;
        const u16* base = arr ? Al : Ah;
        gsrc[4 + p] = base + (size_t)row * HID + scl * 8;
        ldst[4 + p] = arr * 8192 + half * 4096 + sb * 512;
    }
    // read-side lane base (per-lane constant; swizzled chunk)
    const int cpr = q8 ^ ((tl >> 1) & 3);
    const u32 lof = (u32)(tl * 32 + cpr * 8);
    const u32 rA  = (u32)(wm * 4096) + lof;                       // Ah; Al at +8192
    const u32 rB  = 16384u + (u32)((wn >> 1) * 4096 + (wn & 1) * 2048) + lof;  // Bh; Bl +8192

    f32x4 zero = {0.f, 0.f, 0.f, 0.f};
    f32x4 acc[8][4];
#pragma unroll
    for (int i = 0; i < 8; ++i)
#pragma unroll
        for (int j = 0; j < 4; ++j) acc[i][j] = zero;

    // prologue: tile 0 -> buf 0, chunks in ledger order c0..c7
#pragma unroll
    for (int c = 0; c < 8; ++c) gld_lds16(gsrc[c], sm + ldst[c]);
    asm volatile("s_waitcnt vmcnt(3)" ::: "memory");   // c0..c4 done
    asm volatile("s_barrier" ::: "memory");

    // register frags: B persistent per tile; A double-set (X/Y) pipelined
    bf16x8 bh[4], bl[4];
    bf16x8 aXh0, aXh1, aXl0, aXl1, aYh0, aYh1, aYl0, aYl1;
#pragma unroll
    for (int fn = 0; fn < 4; ++fn) {
        bh[fn] = *(const bf16x8*)(sm + rB + fn * 512);
        bl[fn] = *(const bf16x8*)(sm + rB + 8192 + fn * 512);
    }
    aXh0 = *(const bf16x8*)(sm + rA + 0 * 512);
    aXh1 = *(const bf16x8*)(sm + rA + 1 * 512);
    aXl0 = *(const bf16x8*)(sm + rA + 8192 + 0 * 512);
    aXl1 = *(const bf16x8*)(sm + rA + 8192 + 1 * 512);

    for (int t = 0; t < 32; ++t) {
        const u16* smr = sm + ((t & 1) ? 32768u : 0u);
        u16*       smw = sm + ((t & 1) ? 0u : 32768u);
        const int  kn  = (t + 1) * 32;   // tile 32 staging reads slack space (safe, never consumed)
        // ---- phase 0 (uses X; mid-cluster loads Y <- phase1 frags of tile t)
        gld_lds16(gsrc[0] + kn, smw + ldst[0]);
        gld_lds16(gsrc[1] + kn, smw + ldst[1]);
        gld_lds16(gsrc[2] + kn, smw + ldst[2]);
        asm volatile("s_waitcnt vmcnt(5)" ::: "memory");
        asm volatile("s_barrier" ::: "memory");
        __builtin_amdgcn_sched_barrier(0);
        __builtin_amdgcn_s_setprio(1);
        MFROW(0, aXh0, bh) MFROW(1, aXh1, bh)
        aYh0 = *(const bf16x8*)(smr + rA + 2 * 512);
        aYh1 = *(const bf16x8*)(smr + rA + 3 * 512);
        aYl0 = *(const bf16x8*)(smr + rA + 8192 + 2 * 512);
        aYl1 = *(const bf16x8*)(smr + rA + 8192 + 3 * 512);
        MFROW(0, aXl0, bh) MFROW(1, aXl1, bh)
        MFROW(0, aXh0, bl) MFROW(1, aXh1, bl)
        __builtin_amdgcn_s_setprio(0);
        // ---- phase 1 (uses Y; mid-cluster loads X <- phase2 frags)
        gld_lds16(gsrc[3] + kn, smw + ldst[3]);
        gld_lds16(gsrc[4] + kn, smw + ldst[4]);
        asm volatile("s_waitcnt vmcnt(6)" ::: "memory");
        asm volatile("s_barrier" ::: "memory");
        __builtin_amdgcn_sched_barrier(0);
        __builtin_amdgcn_s_setprio(1);
        MFROW(2, aYh0, bh) MFROW(3, aYh1, bh)
        aXh0 = *(const bf16x8*)(smr + rA + 4 * 512);
        aXh1 = *(const bf16x8*)(smr + rA + 5 * 512);
        aXl0 = *(const bf16x8*)(smr + rA + 8192 + 4 * 512);
        aXl1 = *(const bf16x8*)(smr + rA + 8192 + 5 * 512);
        MFROW(2, aYl0, bh) MFROW(3, aYl1, bh)
        MFROW(2, aYh0, bl) MFROW(3, aYh1, bl)
        __builtin_amdgcn_s_setprio(0);
        // ---- phase 2 (uses X; mid-cluster loads Y <- phase3 frags)
        gld_lds16(gsrc[5] + kn, smw + ldst[5]);
        gld_lds16(gsrc[6] + kn, smw + ldst[6]);
        asm volatile("s_waitcnt vmcnt(7)" ::: "memory");
        asm volatile("s_barrier" ::: "memory");
        __builtin_amdgcn_sched_barrier(0);
        __builtin_amdgcn_s_setprio(1);
        MFROW(4, aXh0, bh) MFROW(5, aXh1, bh)
        aYh0 = *(const bf16x8*)(smr + rA + 6 * 512);
        aYh1 = *(const bf16x8*)(smr + rA + 7 * 512);
        aYl0 = *(const bf16x8*)(smr + rA + 8192 + 6 * 512);
        aYl1 = *(const bf16x8*)(smr + rA + 8192 + 7 * 512);
        MFROW(4, aXl0, bh) MFROW(5, aXl1, bh)
        MFROW(4, aXh0, bl) MFROW(5, aXh1, bl)
        __builtin_amdgcn_s_setprio(0);
        // ---- phase 3 (uses Y; mid-cluster loads X <- tile t+1; tail reloads B)
        gld_lds16(gsrc[7] + kn, smw + ldst[7]);
        asm volatile("s_waitcnt vmcnt(3)" ::: "memory");   // t+1:c0..c4 landed
        asm volatile("s_barrier" ::: "memory");
        __builtin_amdgcn_sched_barrier(0);
        __builtin_amdgcn_s_setprio(1);
        MFROW(6, aYh0, bh) MFROW(7, aYh1, bh)
        aXh0 = *(const bf16x8*)(smw + rA + 0 * 512);
        aXh1 = *(const bf16x8*)(smw + rA + 1 * 512);
        aXl0 = *(const bf16x8*)(smw + rA + 8192 + 0 * 512);
        aXl1 = *(const bf16x8*)(smw + rA + 8192 + 1 * 512);
        MFROW(6, aYl0, bh) MFROW(7, aYl1, bh)
        MFROW(6, aYh0, bl) MFROW(7, aYh1, bl)
        __builtin_amdgcn_s_setprio(0);
#pragma unroll
        for (int fn = 0; fn < 4; ++fn) {
            bh[fn] = *(const bf16x8*)(smw + rB + fn * 512);
            bl[fn] = *(const bf16x8*)(smw + rB + 8192 + fn * 512);
        }
        asm volatile("s_barrier" ::: "memory");   // bar2: iteration boundary (buffer swap)
    }

    // fused L3: per row, partial dot over this wave's 64-col window
    const int slot = bx * 4 + wn;   // 0..15, window cols = slot*64 (same as before)
#pragma unroll
    for (int fm = 0; fm < 8; ++fm) {
#pragma unroll
        for (int r = 0; r < 4; ++r) {
            int grow = bm + wm * 128 + fm * 16 + q8 * 4 + r;
            float l0 = 0.f, l1 = 0.f, l2 = 0.f;
#pragma unroll
            for (int fn = 0; fn < 4; ++fn) {
                int gcol = bn + wn * 64 + fn * 16 + tl;
                float v = fmaxf(acc[fm][fn][r] + bs2[gcol], 0.f);
                const float* w3 = Ws3 + gcol * 3;
                l0 = fmaf(v, w3[0], l0);
                l1 = fmaf(v, w3[1], l1);
                l2 = fmaf(v, w3[2], l2);
            }
#pragma unroll
            for (int off = 8; off > 0; off >>= 1) {
                l0 += __shfl_down(l0, off, 16);
                l1 += __shfl_down(l1, off, 16);
                l2 += __shfl_down(l2, off, 16);
            }
            if (tl == 0 && grow < M) {
                float* dst = part + ((size_t)grow * 16 + slot) * 3;
                dst[0] = l0; dst[1] = l1; dst[2] = l2;
            }
        }
    }
    asm volatile("s_waitcnt vmcnt(0)" ::: "memory");   // drain tail staging before exit
}

// ---------------------------------------------------------------------------
// Gathered pair layer-1, split-K over p: TO2[p][r] = xh[toks[r + p*1024]]@B(p)
// dbuf + counted vmcnt(2) (no per-K-step drain).
// ---------------------------------------------------------------------------
__global__ __launch_bounds__(256) void k_pairL1(
    const u16* __restrict__ xh, const u16* __restrict__ Wp1T4,
    float* __restrict__ TO2, const int* __restrict__ toks)
{
    __shared__ __align__(16) u16 sm[2 * 4096];      // dbuf x (A 4KB | B 4KB)
    const int tid = threadIdx.x;
    const int bid = blockIdx.x;
    const int p = bid >> 8;                  // 0/1
    const int bx = bid & 15, by = (bid >> 4) & 15;
    const int bm = by * 64, bn = bx * 64;
    const int wave = tid >> 6, lane = tid & 63;
    const int wr = wave >> 1, wc = wave & 1;
    const int q = lane >> 4, tl = lane & 15;
    const bool isO = bm >= 512;

    f32x4 zero = {0.f, 0.f, 0.f, 0.f};
    f32x4 acc[2][2];
#pragma unroll
    for (int i = 0; i < 2; ++i)
#pragma unroll
        for (int j = 0; j < 2; ++j) acc[i][j] = zero;

    const int srow = tid >> 2;
    const int scol = (tid & 3) * 8;
    const u32 oA = wave * 512;
    const u32 oB = 2048 + wave * 512;

    int arow = toks[bm + srow + p * 1024];    // per-lane row gather
    const u16* gA = xh + (size_t)arow * DIM + scol;
    const u16* gB = Wp1T4 + ((size_t)((isO ? 2 : 0) + p) * 1024 + bn + srow) * DIM + scol;

    // prologue: tile 0 -> buf 0
    gld_lds16(gA, sm + oA);
    gld_lds16(gB, sm + oB);
    asm volatile("s_waitcnt vmcnt(0)" ::: "memory");
    asm volatile("s_barrier" ::: "memory");

    const int NT = DIM / 32;   // 24
    for (int kt = 0; kt < NT; ++kt) {
        const u16* smr = sm + ((kt & 1) ? 4096u : 0u);
        u16*       smw = sm + ((kt & 1) ? 0u : 4096u);
        if (kt < NT - 1) {
            const int k0 = (kt + 1) * 32;
            gld_lds16(gA + k0, smw + oA);
            gld_lds16(gB + k0, smw + oB);
            asm volatile("s_waitcnt vmcnt(2)" ::: "memory");
        } else {
            asm volatile("s_waitcnt vmcnt(0)" ::: "memory");
        }
        asm volatile("s_barrier" ::: "memory");
        bf16x8 af[2], bf[2];
#pragma unroll
        for (int t = 0; t < 2; ++t) {
            af[t] = *(const bf16x8*)(smr + (wr*32 + t*16 + tl) * 32 + q*8);
            bf[t] = *(const bf16x8*)(smr + 2048 + (wc*32 + t*16 + tl) * 32 + q*8);
        }
#pragma unroll
        for (int ti = 0; ti < 2; ++ti)
#pragma unroll
            for (int tj = 0; tj < 2; ++tj)
                acc[ti][tj] = __builtin_amdgcn_mfma_f32_16x16x32_bf16(af[ti], bf[tj], acc[ti][tj], 0, 0, 0);
        asm volatile("s_barrier" ::: "memory");
    }
    float* dstb = TO2 + (size_t)p * 1024 * HID;
#pragma unroll
    for (int ti = 0; ti < 2; ++ti) {
#pragma unroll
        for (int tj = 0; tj < 2; ++tj) {
            int gcol = bn + wc*32 + tj*16 + tl;
#pragma unroll
            for (int r = 0; r < 4; ++r) {
                int grow = bm + wr*32 + ti*16 + q*4 + r;
                dstb[(size_t)grow * HID + gcol] = acc[ti][tj][r];
            }
        }
    }
}

// h1s = relu(XALL[b,start,0:1024] + XALL[b,end-1,1024:2048] + wtabS[w-1]) -> split bf16
__global__ __launch_bounds__(256) void k_build_h1s(
    const float* __restrict__ XALL, const float* __restrict__ wtabS,
    u16* __restrict__ h1h, u16* __restrict__ h1l)
{
    int r = blockIdx.x;                 // 0..16159
    int b = r / NSPAN, s = r - b * NSPAN;
    int st, en, w; span_decode(s, st, en, w);
    const float4* xs = (const float4*)(XALL + (size_t)(b*SEQ + st) * 2048);
    const float4* xe = (const float4*)(XALL + (size_t)(b*SEQ + en - 1) * 2048 + 1024);
    const float4* wt = (const float4*)(wtabS + (size_t)(w-1) * HID);
    int t = threadIdx.x;
    float4 a = xs[t], bz = xe[t], c = wt[t];
    float v0 = fmaxf(a.x + bz.x + c.x, 0.f);
    float v1 = fmaxf(a.y + bz.y + c.y, 0.f);
    float v2 = fmaxf(a.z + bz.z + c.z, 0.f);
    float v3 = fmaxf(a.w + bz.w + c.w, 0.f);
    u16 h0,l0,h1,l1,h2,l2,h3,l3;
    splitbf(v0,h0,l0); splitbf(v1,h1,l1); splitbf(v2,h2,l2); splitbf(v3,h3,l3);
    size_t base = (size_t)r * HID + t * 4;
    *(uint2*)(h1h + base) = make_uint2((u32)h0 | ((u32)h1 << 16), (u32)h2 | ((u32)h3 << 16));
    *(uint2*)(h1l + base) = make_uint2((u32)l0 | ((u32)l1 << 16), (u32)l2 | ((u32)l3 << 16));
}

// ---------------------------------------------------------------------------
// k_topk (fused with span reduce+softmax): reduces partS (fixed order), writes
// out[], packs keys, bitonic-sorts 2048 u64 keys, emits top-64 + token maps.
// 1024 threads: same compare-exchange network (bit-exact), 2 iters/step.
// ---------------------------------------------------------------------------
__global__ __launch_bounds__(1024) void k_topk(
    const float* __restrict__ partS, const float* __restrict__ bs3,
    float* __restrict__ out, int* __restrict__ t_idx, int* __restrict__ o_idx,
    int* __restrict__ toks)
{
    int b = blockIdx.x >> 1;
    int head = 1 + (blockIdx.x & 1);
    int* outp = (head == 1 ? t_idx : o_idx) + b * NZ;
    __shared__ u64 keys[2048];
    int tid = threadIdx.x;
#pragma unroll
    for (int ii = 0; ii < 2; ++ii) {
        int s = tid + ii * 1024;          // 0..2047
        u32 fb = 0;
        if (s < NSPAN) {
            const float* p = partS + (size_t)(b * NSPAN + s) * 48;
            float s0 = bs3[0], s1 = bs3[1], s2 = bs3[2];
#pragma unroll
            for (int t = 0; t < 16; ++t) {
                s0 += p[t*3]; s1 += p[t*3+1]; s2 += p[t*3+2];
            }
            float m = fmaxf(s0, fmaxf(s1, s2));
            float e0 = expf(s0 - m), e1 = expf(s1 - m), e2 = expf(s2 - m);
            float inv = 1.f / (e0 + e1 + e2);
            float p0 = e0 * inv, p1 = e1 * inv, p2 = e2 * inv;
            float* o = out + (size_t)(b * NSPAN + s) * 3;
            o[0] = p0; o[1] = p1; o[2] = p2;
            union { float f; u32 u; } x;
            x.f = (head == 1) ? p1 : p2;
            fb = x.u;
        }
        keys[s] = ((u64)fb << 32) | (u64)(0xFFFFFFFFu - (u32)s);
    }
    __syncthreads();
    for (int k = 2; k <= 2048; k <<= 1) {
        for (int j = k >> 1; j > 0; j >>= 1) {
#pragma unroll
            for (int ii = 0; ii < 2; ++ii) {
                int i = tid + ii * 1024;
                int ixj = i ^ j;
                if (ixj > i) {
                    u64 a = keys[i], c = keys[ixj];
                    bool desc = (i & k) == 0;
                    bool wrong = desc ? (a < c) : (a > c);
                    if (wrong) { keys[i] = c; keys[ixj] = a; }
                }
            }
            __syncthreads();
        }
    }
    if (tid < NZ) {
        u64 key = keys[tid];
        int fi = (int)(0xFFFFFFFFu - (u32)(key & 0xFFFFFFFFu));
        if (fi < 0 || fi >= NSPAN) fi = 0;   // paranoia
        outp[tid] = fi;
        int st, en, w; span_decode(fi, st, en, w);
        int base = (head == 1 ? 0 : 512) + b * NZ + tid;
        toks[base] = b * SEQ + st;
        toks[1024 + base] = b * SEQ + en - 1;
    }
}

// ---------------------------------------------------------------------------
// k_build_h1p v2 (LDS-tiled): one block per (b, 8 i's, 4 j's) -> 32 rows.
// ---------------------------------------------------------------------------
__global__ __launch_bounds__(256) void k_build_h1p(
    const float* __restrict__ TO2, const int* __restrict__ t_idx, const int* __restrict__ o_idx,
    const float* __restrict__ wtabPt, const float* __restrict__ wtabPo,
    const float* __restrict__ dtab, u16* __restrict__ h1p)
{
    __shared__ float Ts[8][HID];    // 32 KB
    __shared__ float Os[4][HID];    // 16 KB
    const int bid = blockIdx.x;     // 1024 = 8 b x 8 it x 16 jt
    const int b = bid >> 7;
    const int it = (bid >> 4) & 7;
    const int jt = bid & 15;
    const int i0 = it * 8, j0 = jt * 4;
    const int tid = threadIdx.x;
    const int k4 = tid * 4;
    const size_t PS = (size_t)1024 * HID;

    int tinfo[8][2];                // (ta, tb) per i
    int oinfo[4][2];                // (oc, od) per j
#pragma unroll
    for (int r = 0; r < 8; ++r) {
        int i = i0 + r;
        int ts = t_idx[b*64 + i];
        int ta, tb, wt; span_decode(ts, ta, tb, wt);
        tinfo[r][0] = ta; tinfo[r][1] = tb;
        float4 t0 = *(const float4*)(TO2 + (size_t)(b*64 + i) * HID + k4);
        float4 t1 = *(const float4*)(TO2 + PS + (size_t)(b*64 + i) * HID + k4);
        float4 pp = *(const float4*)(wtabPt + (size_t)(wt-1) * HID + k4);
        Ts[r][k4+0] = t0.x + t1.x + pp.x;
        Ts[r][k4+1] = t0.y + t1.y + pp.y;
        Ts[r][k4+2] = t0.z + t1.z + pp.z;
        Ts[r][k4+3] = t0.w + t1.w + pp.w;
    }
#pragma unroll
    for (int r = 0; r < 4; ++r) {
        int j = j0 + r;
        int os = o_idx[b*64 + j];
        int oc, od, wo; span_decode(os, oc, od, wo);
        oinfo[r][0] = oc; oinfo[r][1] = od;
        float4 o0 = *(const float4*)(TO2 + (size_t)(512 + b*64 + j) * HID + k4);
        float4 o1 = *(const float4*)(TO2 + PS + (size_t)(512 + b*64 + j) * HID + k4);
        float4 qq = *(const float4*)(wtabPo + (size_t)(wo-1) * HID + k4);
        Os[r][k4+0] = o0.x + o1.x + qq.x;
        Os[r][k4+1] = o0.y + o1.y + qq.y;
        Os[r][k4+2] = o0.z + o1.z + qq.z;
        Os[r][k4+3] = o0.w + o1.w + qq.w;
    }
    __syncthreads();

#pragma unroll
    for (int ri = 0; ri < 8; ++ri) {
#pragma unroll
        for (int rj = 0; rj < 4; ++rj) {
            int ta = tinfo[ri][0], tb = tinfo[ri][1];
            int oc = oinfo[rj][0], od = oinfo[rj][1];
            int d1 = tb - oc; d1 = d1 < 0 ? -d1 : d1;
            int d2 = ta - od; d2 = d2 < 0 ? -d2 : d2;
            int dist = d1 < d2 ? d1 : d2;
            int db = dbucket(dist);
            const float4 dd = *(const float4*)(dtab + (size_t)db * HID + k4);
            float vx = fmaxf(Ts[ri][k4+0] + Os[rj][k4+0] + dd.x, 0.f);
            float vy = fmaxf(Ts[ri][k4+1] + Os[rj][k4+1] + dd.y, 0.f);
            float vz = fmaxf(Ts[ri][k4+2] + Os[rj][k4+2] + dd.z, 0.f);
            float vw = fmaxf(Ts[ri][k4+3] + Os[rj][k4+3] + dd.w, 0.f);
            u32 p0 = (u32)f2bf(vx) | ((u32)f2bf(vy) << 16);
            u32 p1 = (u32)f2bf(vz) | ((u32)f2bf(vw) << 16);
            int row = b * 4096 + (i0 + ri) * 64 + (j0 + rj);
            *(uint2*)(h1p + (size_t)row * HID + k4) = make_uint2(p0, p1);
        }
    }
}

// ---------------------------------------------------------------------------
// Pair layer-2 GEMM v3.4 (intra-cluster interleave): 256x256 tile, 8 waves,
// BK=64, dbuf, 4 phases x 16 MFMA. Next-phase A ds_reads mid-cluster; phase-3
// X-loads mid-cluster (smw valid post vmcnt(3)); B-reload tail (WAR). Ledger
// {5,6,7,3}, issues 3/2/2/1. Per-acc k-order unchanged (bit-identical).
// Fused layer-3 epilogue, 16 slots.
// ---------------------------------------------------------------------------
__global__ __launch_bounds__(512, 2) void k_pair_l2(
    const u16* __restrict__ Abf, const u16* __restrict__ BT,
    const float* __restrict__ bp2, const float* __restrict__ Wp3,
    float* __restrict__ part)
{
    __shared__ __align__(16) u16 sm[65536];            // 128 KiB, 2 bufs
    const int tid = threadIdx.x;
    const int swz = (blockIdx.x & 7) * 64 + (blockIdx.x >> 3);   // 512 wgs, 8 XCDs
    const int by = swz >> 2, bx = swz & 3;
    const int bm = by * 256, bn = bx * 256;
    const int wave = tid >> 6, lane = tid & 63;
    const int wm = wave >> 2, wn = wave & 3;
    const int tl = lane & 15, q8 = lane >> 4;

    const int sr  = lane >> 2;
    const int scs = lane & 3;
    const int scl = scs ^ ((sr >> 1) & 3);
    // chunk table: c0..c3 = B (half0 sb=w, half0 sb=8+w, half1 sb=w, half1 sb=8+w),
    // c4+p = A group p (half=w>>2, sb=4p+(w&3));  sb = rowsub*2 + ks
    const u16* gsrc[8];
    u32 ldst[8];
#pragma unroll
    for (int c = 0; c < 4; ++c) {
        int half = c >> 1;
        int sb   = (c & 1) * 8 + wave;
        int row  = bn + half * 128 + (sb >> 1) * 16 + sr;
        gsrc[c] = BT + (size_t)row * HID + (sb & 1) * 32 + scl * 8;
        ldst[c] = 16384 + half * 8192 + sb * 512;
    }
#pragma unroll
    for (int p = 0; p < 4; ++p) {
        int half = wave >> 2;
        int sb   = 4 * p + (wave & 3);
        int row  = bm + half * 128 + (sb >> 1) * 16 + sr;
        gsrc[4 + p] = Abf + (size_t)row * HID + (sb & 1) * 32 + scl * 8;
        ldst[4 + p] = half * 8192 + sb * 512;
    }
    const int cpr = q8 ^ ((tl >> 1) & 3);
    const u32 lof = (u32)(tl * 32 + cpr * 8);
    const u32 rA  = (u32)(wm * 8192) + lof;
    const u32 rB  = 16384u + (u32)((wn >> 1) * 8192 + (wn & 1) * 4096) + lof;

    f32x4 zero = {0.f, 0.f, 0.f, 0.f};
    f32x4 acc[8][4];
#pragma unroll
    for (int i = 0; i < 8; ++i)
#pragma unroll
        for (int j = 0; j < 4; ++j) acc[i][j] = zero;

    // prologue: tile 0 -> buf 0
#pragma unroll
    for (int c = 0; c < 8; ++c) gld_lds16(gsrc[c], sm + ldst[c]);
    asm volatile("s_waitcnt vmcnt(3)" ::: "memory");   // c0..c4 done
    asm volatile("s_barrier" ::: "memory");

    bf16x8 b0[4], b1[4];
    bf16x8 xa00, xa01, xa10, xa11, ya00, ya01, ya10, ya11;
#pragma unroll
    for (int fn = 0; fn < 4; ++fn) {
        b0[fn] = *(const bf16x8*)(sm + rB + (fn * 2 + 0) * 512);
        b1[fn] = *(const bf16x8*)(sm + rB + (fn * 2 + 1) * 512);
    }
    xa00 = *(const bf16x8*)(sm + rA + 0 * 512);
    xa01 = *(const bf16x8*)(sm + rA + 1 * 512);
    xa10 = *(const bf16x8*)(sm + rA + 2 * 512);
    xa11 = *(const bf16x8*)(sm + rA + 3 * 512);

    for (int t = 0; t < 16; ++t) {
        const u16* smr = sm + ((t & 1) ? 32768u : 0u);
        u16*       smw = sm + ((t & 1) ? 0u : 32768u);
        const int  kn  = (t + 1) * 64;   // tile 16 staging reads slack space (safe, never consumed)
        // ---- phase 0 (uses X; mid-cluster loads Y <- fm2,3)
        gld_lds16(gsrc[0] + kn, smw + ldst[0]);
        gld_lds16(gsrc[1] + kn, smw + ldst[1]);
        gld_lds16(gsrc[2] + kn, smw + ldst[2]);
        asm volatile("s_waitcnt vmcnt(5)" ::: "memory");
        asm volatile("s_barrier" ::: "memory");
        __builtin_amdgcn_sched_barrier(0);
        __builtin_amdgcn_s_setprio(1);
        MFROW(0, xa00, b0) MFROW(1, xa10, b0)
        ya00 = *(const bf16x8*)(smr + rA + 4 * 512);
        ya01 = *(const bf16x8*)(smr + rA + 5 * 512);
        ya10 = *(const bf16x8*)(smr + rA + 6 * 512);
        ya11 = *(const bf16x8*)(smr + rA + 7 * 512);
        MFROW(0, xa01, b1) MFROW(1, xa11, b1)
        __builtin_amdgcn_s_setprio(0);
        // ---- phase 1 (uses Y; mid-cluster loads X <- fm4,5)
        gld_lds16(gsrc[3] + kn, smw + ldst[3]);
        gld_lds16(gsrc[4] + kn, smw + ldst[4]);
        asm volatile("s_waitcnt vmcnt(6)" ::: "memory");
        asm volatile("s_barrier" ::: "memory");
        __builtin_amdgcn_sched_barrier(0);
        __builtin_amdgcn_s_setprio(1);
        MFROW(2, ya00, b0) MFROW(3, ya10, b0)
        xa00 = *(const bf16x8*)(smr + rA + 8 * 512);
        xa01 = *(const bf16x8*)(smr + rA + 9 * 512);
        xa10 = *(const bf16x8*)(smr + rA + 10 * 512);
        xa11 = *(const bf16x8*)(smr + rA + 11 * 512);
        MFROW(2, ya01, b1) MFROW(3, ya11, b1)
        __builtin_amdgcn_s_setprio(0);
        // ---- phase 2 (uses X; mid-cluster loads Y <- fm6,7)
        gld_lds16(gsrc[5] + kn, smw + ldst[5]);
        gld_lds16(gsrc[6] + kn, smw + ldst[6]);
        asm volatile("s_waitcnt vmcnt(7)" ::: "memory");
        asm volatile("s_barrier" ::: "memory");
        __builtin_amdgcn_sched_barrier(0);
        __builtin_amdgcn_s_setprio(1);
        MFROW(4, xa00, b0) MFROW(5, xa10, b0)
        ya00 = *(const bf16x8*)(smr + rA + 12 * 512);
        ya01 = *(const bf16x8*)(smr + rA + 13 * 512);
        ya10 = *(const bf16x8*)(smr + rA + 14 * 512);
        ya11 = *(const bf16x8*)(smr + rA + 15 * 512);
        MFROW(4, xa01, b1) MFROW(5, xa11, b1)
        __builtin_amdgcn_s_setprio(0);
        // ---- phase 3 (uses Y; mid-cluster loads X <- tile t+1; tail reloads B)
        gld_lds16(gsrc[7] + kn, smw + ldst[7]);
        asm volatile("s_waitcnt vmcnt(3)" ::: "memory");   // t+1:c0..c4 landed
        asm volatile("s_barrier" ::: "memory");
        __builtin_amdgcn_sched_barrier(0);
        __builtin_amdgcn_s_setprio(1);
        MFROW(6, ya00, b0) MFROW(7, ya10, b0)
        xa00 = *(const bf16x8*)(smw + rA + 0 * 512);
        xa01 = *(const bf16x8*)(smw + rA + 1 * 512);
        xa10 = *(const bf16x8*)(smw + rA + 2 * 512);
        xa11 = *(const bf16x8*)(smw + rA + 3 * 512);
        MFROW(6, ya01, b1) MFROW(7, ya11, b1)
        __builtin_amdgcn_s_setprio(0);
#pragma unroll
        for (int fn = 0; fn < 4; ++fn) {
            b0[fn] = *(const bf16x8*)(smw + rB + (fn * 2 + 0) * 512);
            b1[fn] = *(const bf16x8*)(smw + rB + (fn * 2 + 1) * 512);
        }
        asm volatile("s_barrier" ::: "memory");   // bar2: iteration boundary (buffer swap)
    }

    // fused L3 projection
    const int slot = bx * 4 + wn;   // window cols = slot*64 (same as before)
#pragma unroll
    for (int fm = 0; fm < 8; ++fm) {
#pragma unroll
        for (int r = 0; r < 4; ++r) {
            int grow = bm + wm * 128 + fm * 16 + q8 * 4 + r;
            float l0 = 0.f, l1 = 0.f, l2 = 0.f, l3 = 0.f;
#pragma unroll
            for (int fn = 0; fn < 4; ++fn) {
                int gcol = bn + wn * 64 + fn * 16 + tl;
                float v = fmaxf(acc[fm][fn][r] + bp2[gcol], 0.f);
                const float4 w = *(const float4*)(Wp3 + gcol * 4);
                l0 = fmaf(v, w.x, l0); l1 = fmaf(v, w.y, l1);
                l2 = fmaf(v, w.z, l2); l3 = fmaf(v, w.w, l3);
            }
#pragma unroll
            for (int off = 8; off > 0; off >>= 1) {
                l0 += __shfl_down(l0, off, 16);
                l1 += __shfl_down(l1, off, 16);
                l2 += __shfl_down(l2, off, 16);
                l3 += __shfl_down(l3, off, 16);
            }
            if (tl == 0) {
                float* dst = part + ((size_t)grow * 16 + slot) * 4;
                dst[0] = l0; dst[1] = l1; dst[2] = l2; dst[3] = l3;
            }
        }
    }
    asm volatile("s_waitcnt vmcnt(0)" ::: "memory");   // drain tail staging before exit
}

// reduce 16 slots (fixed order) + softmax -> out[48480 + r*4 + c]
__global__ __launch_bounds__(256) void k_pair_red(
    const float* __restrict__ part, const float* __restrict__ bp3,
    float* __restrict__ out)
{
    int r = blockIdx.x * 256 + threadIdx.x;   // 32768 = 128*256 exact
    const float4* p = (const float4*)(part + (size_t)r * 64);
    float s0 = bp3[0], s1 = bp3[1], s2 = bp3[2], s3 = bp3[3];
#pragma unroll
    for (int t = 0; t < 16; ++t) {
        float4 v = p[t];
        s0 += v.x; s1 += v.y; s2 += v.z; s3 += v.w;
    }
    float m = fmaxf(fmaxf(s0, s1), fmaxf(s2, s3));
    float e0 = expf(s0 - m), e1 = expf(s1 - m), e2 = expf(s2 - m), e3 = expf(s3 - m);
    float inv = 1.f / (e0 + e1 + e2 + e3);
    float* o = out + (size_t)r * 4;
    o[0] = e0 * inv; o[1] = e1 * inv; o[2] = e2 * inv; o[3] = e3 * inv;
}

extern "C" void kernel_launch(void* const* d_in, const int* in_sizes, int n_in,
                              void* d_out, int out_size, void* d_ws, size_t ws_size,
                              hipStream_t stream)
{
    const float* x    = (const float*)d_in[0];
    const float* wemb = (const float*)d_in[1];
    const float* demb = (const float*)d_in[2];
    const float* Ws1  = (const float*)d_in[3];
    const float* bs1  = (const float*)d_in[4];
    const float* Ws2  = (const float*)d_in[5];
    const float* bs2  = (const float*)d_in[6];
    const float* Ws3  = (const float*)d_in[7];
    const float* bs3  = (const float*)d_in[8];
    const float* Wp1  = (const float*)d_in[9];
    const float* bp1  = (const float*)d_in[10];
    const float* Wp2  = (const float*)d_in[11];
    const float* bp2  = (const float*)d_in[12];
    const float* Wp3  = (const float*)d_in[13];
    const float* bp3  = (const float*)d_in[14];
    float* out = (float*)d_out;
    char* ws = (char*)d_ws;

    // ---- workspace arena, lifetime-aliased (~162 MB) ----
    const size_t RSZ = (size_t)32768 * HID * 2;   // 64 MiB
    size_t off = 0;
    auto alloc = [&](size_t bytes) -> void* {
        void* p = ws + off;
        off += (bytes + 255) & ~(size_t)255;
        return p;
    };
    char* R1 = (char*)alloc(RSZ);
    char* R2 = (char*)alloc(RSZ);
    u16*   h1h  = (u16*)R1;                              // 33.1 MB
    u16*   h1l  = (u16*)(R1 + (size_t)16160 * HID * 2);  // 33.1 MB
    float* XALL = (float*)R2;                            // 16 MiB
    u16*   xl   = (u16*)(R2 + (16u << 20));              // 3 MB
    u16*   W1Th = (u16*)(R2 + (19u << 20));              // 3 MB
    u16*   W1Tl = (u16*)(R2 + (22u << 20));              // 3 MB
    u16*   h1p  = (u16*)R2;                              // 64 MiB (after the above dead)
    u16*   xh     = (u16*)alloc((size_t)2048 * DIM * 2);     // 3 MB PERSISTENT
    float* TO2    = (float*)alloc((size_t)2 * 1024 * HID * 4);   // 8 MB
    float* partS  = (float*)alloc((size_t)16160 * 16 * 3 * 4);   // 3.1 MB
    float* partP  = (float*)alloc((size_t)32768 * 16 * 4 * 4);   // 8.4 MB
    u16*   W2Th   = (u16*)alloc((size_t)1024 * 1024 * 2);
    u16*   W2Tl   = (u16*)alloc((size_t)1024 * 1024 * 2);
    u16*   Wp2T   = (u16*)alloc((size_t)1024 * 1024 * 2);
    u16*   Wp1T4  = (u16*)alloc((size_t)4 * 1024 * 768 * 2);
    float* wtabS  = (float*)alloc(8 * HID * 4);
    float* wtabPt = (float*)alloc(8 * HID * 4);
    float* wtabPo = (float*)alloc(8 * HID * 4);
    float* dtab   = (float*)alloc(14 * HID * 4);
    int*   t_idx  = (int*)alloc(BATCH * NZ * 4);
    int*   o_idx  = (int*)alloc(BATCH * NZ * 4);
    int*   toks   = (int*)alloc(2048 * 4);
    (void)ws_size; (void)in_sizes; (void)n_in; (void)out_size;

    // prep (fused): x split + tables + all weight transposes
    k_prep<<<12952, 256, 0, stream>>>(x, xh, xl, wemb, demb, bs1, bp1,
                                      wtabS, wtabPt, wtabPo, dtab,
                                      Ws1, W1Th, W1Tl, Ws2, W2Th, W2Tl,
                                      Wp2, Wp2T, Wp1, Wp1T4);

    // layer-1 factorization: XALL = x2d @ [Ws1_top | Ws1_mid] (3-pass split-bf16)
    k_gemm3bf<<<256, 256, 0, stream>>>(xh, xl, 768, W1Th, W1Tl, 768,
                                       XALL, 2048, 2048, 768, 16, 4);
    k_build_h1s<<<16160, 256, 0, stream>>>(XALL, wtabS, h1h, h1l);
    // span layer2 + FUSED layer3 partials: interleaved 4-phase counted-vmcnt
    k_span_l2<<<256, 512, 0, stream>>>(h1h, h1l, W2Th, W2Tl, bs2, Ws3, partS, 16160);
    // fused reduce+softmax+topk+toks (1024-thread bitonic, bit-exact network)
    k_topk<<<16, 1024, 0, stream>>>(partS, bs3, out, t_idx, o_idx, toks);
    // gathered pair layer-1: split-K bf16 MFMA, dbuf counted-vmcnt
    k_pairL1<<<512, 256, 0, stream>>>(xh, Wp1T4, TO2, toks);
    // h1p build: LDS-tiled (8i x 4j per block), 1024 blocks
    k_build_h1p<<<1024, 256, 0, stream>>>(TO2, t_idx, o_idx, wtabPt, wtabPo, dtab, h1p);
    // pair layer2 + FUSED layer3 partials: interleaved 4-phase counted-vmcnt
    k_pair_l2<<<512, 512, 0, stream>>>(h1p, Wp2T, bp2, Wp3, partP);
    k_pair_red<<<128, 256, 0, stream>>>(partP, bp3, out + 48480);
}

// Round 7
// 386.909 us; speedup vs baseline: 1.1827x; 1.1827x over previous
//
#include <hip/hip_runtime.h>
#include <cstdint>
#include <cstddef>

#define BATCH 8
#define SEQ   256
#define DIM   768
#define NSPAN 2020
#define HID   1024
#define NZ    64

typedef unsigned short u16;
typedef unsigned int   u32;
typedef unsigned long long u64;

typedef __bf16 bf16x8 __attribute__((ext_vector_type(8)));
typedef float  f32x4  __attribute__((ext_vector_type(4)));

__device__ __forceinline__ u16 f2bf(float f) {
    union { float f; u32 u; } x; x.f = f;
    u32 r = x.u + 0x7fffu + ((x.u >> 16) & 1u);
    return (u16)(r >> 16);
}
__device__ __forceinline__ float bf2f(u16 b) {
    union { u32 u; float f; } x; x.u = ((u32)b) << 16;
    return x.f;
}
// split v = hi + lo (both bf16); residual v-hi is exact in fp32
__device__ __forceinline__ void splitbf(float v, u16& h, u16& l) {
    h = f2bf(v);
    l = f2bf(v - bf2f(h));
}

// async global->LDS, 16B per lane; LDS dest = wave-uniform base + lane*16;
// global src may be per-lane (row gather OK) [m97/m104]
__device__ __forceinline__ void gld_lds16(const void* g, void* l) {
    __builtin_amdgcn_global_load_lds(
        (const __attribute__((address_space(1))) unsigned int*)g,
        (__attribute__((address_space(3))) unsigned int*)l, 16, 0, 0);
}

// span s -> (start, end, width); spans enumerated width-major: w=1..8, starts 0..L-w
__device__ __forceinline__ void span_decode(int s, int& start, int& end, int& w) {
    int off = 0;
#pragma unroll
    for (int wi = 1; wi <= 8; ++wi) {
        int cnt = SEQ - wi + 1;
        if (s < off + cnt) { w = wi; start = s - off; end = start + wi; return; }
        off += cnt;
    }
    w = 8; start = 0; end = 8;
}

// searchsorted(BUCKET_BINS, d, 'right') - 1
__device__ __forceinline__ int dbucket(int d) {
    int b = 0;
    b += (d >= 1);  b += (d >= 2);  b += (d >= 3);  b += (d >= 4);
    b += (d >= 5);  b += (d >= 7);  b += (d >= 8);  b += (d >= 15);
    b += (d >= 16); b += (d >= 31); b += (d >= 32); b += (d >= 63);
    b += (d >= 64);
    return b;
}

// XCD-aware deswizzle: (linear id) % 8 == by % 8 -> all column-blocks of one
// A-row-tile land on the SAME XCD (id%8 round-robin). sft = log2(nbx).
__device__ __forceinline__ void xcd_map(int L, int sft, int& bx, int& by) {
    int grp = L >> (3 + sft);
    int rem = L & ((1 << (3 + sft)) - 1);
    bx = rem >> 3;
    by = (grp << 3) | (rem & 7);
}

// ---------------------------------------------------------------------------
// k_prep (fused): x hi/lo split | bucket tables | all weight transposes.
// ---------------------------------------------------------------------------
__global__ __launch_bounds__(256) void k_prep(
    const float* __restrict__ x,  u16* __restrict__ xh,   u16* __restrict__ xl,
    const float* __restrict__ wemb, const float* __restrict__ demb,
    const float* __restrict__ bs1, const float* __restrict__ bp1,
    float* __restrict__ wtabS, float* __restrict__ wtabPt,
    float* __restrict__ wtabPo, float* __restrict__ dtab,
    const float* __restrict__ Ws1, u16* __restrict__ W1Th, u16* __restrict__ W1Tl,
    const float* __restrict__ Ws2, u16* __restrict__ W2Th, u16* __restrict__ W2Tl,
    const float* __restrict__ Wp2, u16* __restrict__ Wp2T,
    const float* __restrict__ Wp1, u16* __restrict__ Wp1T4)
{
    __shared__ float tile[32][33];
    const int bid = blockIdx.x, tid = threadIdx.x;
    if (bid < 6144) {
        int i = bid * 256 + tid;         // over 2048*768
        u16 h, l; splitbf(x[i], h, l);
        xh[i] = h; xl[i] = l;
        return;
    }
    if (bid < 6296) {
        int t = bid - 6144;              // 0..151
        int row = t >> 2;                // 0..37
        int h = (t & 3) * 256 + tid;     // 0..1023
        const int wb[8] = {1,2,3,4,5,5,6,7};
        if (row < 8) {
            int bk = wb[row];
            float acc = bs1[h];
            for (int j = 0; j < 25; ++j) acc = fmaf(wemb[bk*25+j], Ws1[(size_t)(1536+j)*HID + h], acc);
            wtabS[row*HID + h] = acc;
        } else if (row < 16) {
            int bk = wb[row-8];
            float acc = 0.f;
            for (int j = 0; j < 25; ++j) acc = fmaf(wemb[bk*25+j], Wp1[(size_t)(1536+j)*HID + h], acc);
            wtabPt[(row-8)*HID + h] = acc;
        } else if (row < 24) {
            int bk = wb[row-16];
            float acc = 0.f;
            for (int j = 0; j < 25; ++j) acc = fmaf(wemb[bk*25+j], Wp1[(size_t)(3097+j)*HID + h], acc);
            wtabPo[(row-16)*HID + h] = acc;
        } else {
            int tt = row - 24;           // 0..13
            float acc = bp1[h];
            for (int j = 0; j < 25; ++j) acc = fmaf(demb[tt*25+j], Wp1[(size_t)(3122+j)*HID + h], acc);
            dtab[tt*HID + h] = acc;
        }
        return;
    }
    // transpose jobs
    const int tb = bid - 6296;           // 0..6655
    const int tr = tid >> 3;             // 0..31
    const int tc4 = (tid & 7) * 4;       // 0,4,..,28
    int job, tk, tn, blk = 0;
    if (tb < 1536)      { job = 0; tk = tb % 24; tn = tb / 24; }
    else if (tb < 2560) { job = 1; int t = tb - 1536; tk = t & 31; tn = t >> 5; }
    else if (tb < 3584) { job = 2; int t = tb - 2560; tk = t & 31; tn = t >> 5; }
    else                { job = 3; int t = tb - 3584; blk = t / 768; int r = t - blk * 768; tk = r % 24; tn = r / 24; }
    const int k0 = tk * 32, n0 = tn * 32;

    int k = k0 + tr;
    float4 v;
    if (job == 0) {
        const float* s = (n0 < 1024) ? (Ws1 + (size_t)k * HID + n0)
                                     : (Ws1 + (size_t)(768 + k) * HID + (n0 - 1024));
        v = *(const float4*)(s + tc4);
    } else if (job == 1) {
        v = *(const float4*)(Ws2 + (size_t)k * HID + n0 + tc4);
    } else if (job == 2) {
        v = *(const float4*)(Wp2 + (size_t)k * HID + n0 + tc4);
    } else {
        const int roff[4] = {0, 768, 1561, 2329};   // (T,p0),(T,p1),(O,p0),(O,p1)
        v = *(const float4*)(Wp1 + (size_t)(roff[blk] + k) * HID + n0 + tc4);
    }
    tile[tr][tc4+0] = v.x; tile[tr][tc4+1] = v.y;
    tile[tr][tc4+2] = v.z; tile[tr][tc4+3] = v.w;
    __syncthreads();

    int nn = n0 + tr;
    float w0 = tile[tc4+0][tr], w1 = tile[tc4+1][tr];
    float w2 = tile[tc4+2][tr], w3 = tile[tc4+3][tr];
    if (job == 0) {
        size_t d = (size_t)nn * 768 + k0 + tc4;
        u16 h0,l0,h1,l1,h2,l2,h3,l3;
        splitbf(w0,h0,l0); splitbf(w1,h1,l1); splitbf(w2,h2,l2); splitbf(w3,h3,l3);
        *(uint2*)(W1Th + d) = make_uint2((u32)h0 | ((u32)h1 << 16), (u32)h2 | ((u32)h3 << 16));
        *(uint2*)(W1Tl + d) = make_uint2((u32)l0 | ((u32)l1 << 16), (u32)l2 | ((u32)l3 << 16));
    } else if (job == 1) {
        size_t d = (size_t)nn * 1024 + k0 + tc4;
        u16 h0,l0,h1,l1,h2,l2,h3,l3;
        splitbf(w0,h0,l0); splitbf(w1,h1,l1); splitbf(w2,h2,l2); splitbf(w3,h3,l3);
        *(uint2*)(W2Th + d) = make_uint2((u32)h0 | ((u32)h1 << 16), (u32)h2 | ((u32)h3 << 16));
        *(uint2*)(W2Tl + d) = make_uint2((u32)l0 | ((u32)l1 << 16), (u32)l2 | ((u32)l3 << 16));
    } else if (job == 2) {
        size_t d = (size_t)nn * 1024 + k0 + tc4;
        *(uint2*)(Wp2T + d) = make_uint2((u32)f2bf(w0) | ((u32)f2bf(w1) << 16),
                                         (u32)f2bf(w2) | ((u32)f2bf(w3) << 16));
    } else {
        size_t d = (size_t)blk * 786432 + (size_t)nn * 768 + k0 + tc4;
        *(uint2*)(Wp1T4 + d) = make_uint2((u32)f2bf(w0) | ((u32)f2bf(w1) << 16),
                                          (u32)f2bf(w2) | ((u32)f2bf(w3) << 16));
    }
}

#define MFB __builtin_amdgcn_mfma_f32_16x16x32_bf16
#define MFROW(i, A, B) \
    acc[i][0] = MFB(A, B[0], acc[i][0], 0, 0, 0); \
    acc[i][1] = MFB(A, B[1], acc[i][1], 0, 0, 0); \
    acc[i][2] = MFB(A, B[2], acc[i][2], 0, 0, 0); \
    acc[i][3] = MFB(A, B[3], acc[i][3], 0, 0, 0);

// ---------------------------------------------------------------------------
// Error-compensated split-bf16 MFMA GEMM v2: C = AhBh + AlBh + AhBl (XALL).
// 128x128 tile, 8 waves (2 waves/SIMD), BK=32, 64 KiB dbuf, counted vmcnt(4),
// chunk-XOR LDS swizzle (store: pre-swizzled global col; read: cpr) -> no
// 8-way bank conflicts. Per-acc K-order hh,lh,hl ascending (bit-identical).
// Wave partition: wr=wave>>2 (2 M-halves of 64), wc=wave&3 (4 N-quarters of 32).
// ---------------------------------------------------------------------------
__global__ __launch_bounds__(512) void k_gemm3bf(
    const u16* __restrict__ Ah, const u16* __restrict__ Al, int lda,
    const u16* __restrict__ BTh, const u16* __restrict__ BTl, int ldb,
    float* __restrict__ C, int ldc,
    int M, int K, int nby, int sft)
{
    int bx, by;
    xcd_map(blockIdx.x, sft, bx, by);
    if (by >= nby) return;
    __shared__ __align__(16) u16 sm[2 * 16384];        // 64 KiB dbuf; per buf: Ah[0) Al[4096) Bh[8192) Bl[12288)
    const int tid = threadIdx.x;
    const int bm = by * 128, bn = bx * 128;
    const int wave = tid >> 6, lane = tid & 63;
    const int wr = wave >> 2, wc = wave & 3;
    const int q8 = lane >> 4, tl = lane & 15;

    f32x4 zero = {0.f, 0.f, 0.f, 0.f};
    f32x4 acc[4][2];
#pragma unroll
    for (int i = 0; i < 4; ++i)
#pragma unroll
        for (int j = 0; j < 2; ++j) acc[i][j] = zero;

    // staging: arr = wave>>1 (0:Ah 1:Al 2:Bh 3:Bl), half = wave&1 (row half of 64)
    const int arr  = wave >> 1;
    const int half = wave & 1;
    const int sr   = lane >> 2;
    const int scs  = lane & 3;
    const int scl  = scs ^ ((sr >> 1) & 3);            // pre-swizzled global chunk
    const u16* gsrc[4];
    u32 ldst[4];
#pragma unroll
    for (int j = 0; j < 4; ++j) {
        int row = ((arr < 2) ? bm : bn) + half * 64 + j * 16 + sr;
        if (arr < 2 && row >= M) row = M - 1;
        const u16* base = (arr == 0) ? Ah : (arr == 1) ? Al : (arr == 2) ? BTh : BTl;
        int ld = (arr < 2) ? lda : ldb;
        gsrc[j] = base + (size_t)row * ld + scl * 8;
        ldst[j] = arr * 4096 + half * 2048 + j * 512;
    }
    // read-side: swizzled chunk
    const int cpr = q8 ^ ((tl >> 1) & 3);
    const u32 lof = (u32)(tl * 32 + cpr * 8);

    // prologue: tile 0 -> buf 0
#pragma unroll
    for (int j = 0; j < 4; ++j) gld_lds16(gsrc[j], sm + ldst[j]);
    asm volatile("s_waitcnt vmcnt(0)" ::: "memory");
    asm volatile("s_barrier" ::: "memory");

    const int NT = K >> 5;
    for (int kt = 0; kt < NT; ++kt) {
        const u16* smr = sm + ((kt & 1) ? 16384u : 0u);
        u16*       smw = sm + ((kt & 1) ? 0u : 16384u);
        if (kt < NT - 1) {
            const int k0 = (kt + 1) * 32;
#pragma unroll
            for (int j = 0; j < 4; ++j) gld_lds16(gsrc[j] + k0, smw + ldst[j]);
            asm volatile("s_waitcnt vmcnt(4)" ::: "memory");   // tile kt landed; kt+1 in flight
        } else {
            asm volatile("s_waitcnt vmcnt(0)" ::: "memory");
        }
        asm volatile("s_barrier" ::: "memory");
        __builtin_amdgcn_sched_barrier(0);
        bf16x8 ah[4], al[4], bh[2], bl[2];
#pragma unroll
        for (int fm = 0; fm < 4; ++fm) {
            ah[fm] = *(const bf16x8*)(smr + (wr*4 + fm) * 512 + lof);
            al[fm] = *(const bf16x8*)(smr + 4096 + (wr*4 + fm) * 512 + lof);
        }
#pragma unroll
        for (int fn = 0; fn < 2; ++fn) {
            bh[fn] = *(const bf16x8*)(smr + 8192 + (wc*2 + fn) * 512 + lof);
            bl[fn] = *(const bf16x8*)(smr + 12288 + (wc*2 + fn) * 512 + lof);
        }
#pragma unroll
        for (int fm = 0; fm < 4; ++fm)
#pragma unroll
            for (int fn = 0; fn < 2; ++fn) {
                acc[fm][fn] = MFB(ah[fm], bh[fn], acc[fm][fn], 0, 0, 0);
                acc[fm][fn] = MFB(al[fm], bh[fn], acc[fm][fn], 0, 0, 0);
                acc[fm][fn] = MFB(ah[fm], bl[fn], acc[fm][fn], 0, 0, 0);
            }
        asm volatile("s_barrier" ::: "memory");
    }
    // C/D layout: col = lane&15, row = (lane>>4)*4 + reg  [measured m89/m91]
#pragma unroll
    for (int fm = 0; fm < 4; ++fm) {
#pragma unroll
        for (int fn = 0; fn < 2; ++fn) {
            int gcol = bn + wc*32 + fn*16 + tl;
#pragma unroll
            for (int r = 0; r < 4; ++r) {
                int grow = bm + wr*64 + fm*16 + q8*4 + r;
                if (grow >= M) continue;
                C[(size_t)grow * ldc + gcol] = acc[fm][fn][r];
            }
        }
    }
}

// ---------------------------------------------------------------------------
// Span layer-2 GEMM v3.2 (reg-pipelined phases, R5 proven form): 256x256 tile,
// 8 waves, BK=32, dbuf. Each phase's ds_reads in the PREVIOUS phase's fenced
// post-MFMA tail. Ledger {5,6,7,3}, issues 3/2/2/1. 3-pass split-bf16,
// per-acc order hh,lh,hl ascending K (bit-identical). Fused L3 epilogue.
// ---------------------------------------------------------------------------
__global__ __launch_bounds__(512, 2) void k_span_l2(
    const u16* __restrict__ Ah, const u16* __restrict__ Al,
    const u16* __restrict__ BTh, const u16* __restrict__ BTl,
    const float* __restrict__ bs2, const float* __restrict__ Ws3,
    float* __restrict__ part, int M)
{
    __shared__ __align__(16) u16 sm[65536];            // 128 KiB, 2 bufs
    const int tid = threadIdx.x;
    const int swz = (blockIdx.x & 7) * 32 + (blockIdx.x >> 3);   // 256 wgs, 8 XCDs
    const int by = swz >> 2, bx = swz & 3;
    const int bm = by * 256, bn = bx * 256;
    const int wave = tid >> 6, lane = tid & 63;
    const int wm = wave >> 2, wn = wave & 3;           // 2M x 4N waves
    const int tl = lane & 15, q8 = lane >> 4;

    // stage-side: lane -> (subtile row, stored chunk) ; logical chunk via swizzle
    const int sr  = lane >> 2;
    const int scs = lane & 3;
    const int scl = scs ^ ((sr >> 1) & 3);
    // per-wave chunk table: c0..c3 = B (Bh h0, Bh h1, Bl h0, Bl h1; sb=wave),
    // c4+p = A group for phase p (arr=w>>2, half=(w>>1)&1, sb=2p+(w&1))
    const u16* gsrc[8];
    u32 ldst[8];
#pragma unroll
    for (int c = 0; c < 4; ++c) {
        int arr  = 2 + (c >> 1);           // 2=Bh 3=Bl
        int half = c & 1;
        int sb   = wave;
        int row  = bn + half * 128 + sb * 16 + sr;
        const u16* base = (arr == 2) ? BTh : BTl;
        gsrc[c] = base + (size_t)row * HID + scl * 8;
        ldst[c] = arr * 8192 + half * 4096 + sb * 512;
    }
#pragma unroll
    for (int p = 0; p < 4; ++p) {
        int arr  = wave >> 2;              // 0=Ah 1=Al
        int half = (wave >> 1) & 1;
        int sb   = 2 * p + (wave & 1);
        int row  = bm + half * 128 + sb * 16 + sr;
        if (row >= M) row = M - 1;
        const u16* base = arr ? Al : Ah;
        gsrc[4 + p] = base + (size_t)row * HID + scl * 8;
        ldst[4 + p] = arr * 8192 + half * 4096 + sb * 512;
    }
    // read-side lane base (per-lane constant; swizzled chunk)
    const int cpr = q8 ^ ((tl >> 1) & 3);
    const u32 lof = (u32)(tl * 32 + cpr * 8);
    const u32 rA  = (u32)(wm * 4096) + lof;                       // Ah; Al at +8192
    const u32 rB  = 16384u + (u32)((wn >> 1) * 4096 + (wn & 1) * 2048) + lof;  // Bh; Bl +8192

    f32x4 zero = {0.f, 0.f, 0.f, 0.f};
    f32x4 acc[8][4];
#pragma unroll
    for (int i = 0; i < 8; ++i)
#pragma unroll
        for (int j = 0; j < 4; ++j) acc[i][j] = zero;

    // prologue: tile 0 -> buf 0, chunks in ledger order c0..c7
#pragma unroll
    for (int c = 0; c < 8; ++c) gld_lds16(gsrc[c], sm + ldst[c]);
    asm volatile("s_waitcnt vmcnt(3)" ::: "memory");   // c0..c4 done
    asm volatile("s_barrier" ::: "memory");

    // register frags: B persistent per tile; A double-set (X/Y) pipelined
    bf16x8 bh[4], bl[4];
    bf16x8 aXh0, aXh1, aXl0, aXl1, aYh0, aYh1, aYl0, aYl1;
#pragma unroll
    for (int fn = 0; fn < 4; ++fn) {
        bh[fn] = *(const bf16x8*)(sm + rB + fn * 512);
        bl[fn] = *(const bf16x8*)(sm + rB + 8192 + fn * 512);
    }
    aXh0 = *(const bf16x8*)(sm + rA + 0 * 512);
    aXh1 = *(const bf16x8*)(sm + rA + 1 * 512);
    aXl0 = *(const bf16x8*)(sm + rA + 8192 + 0 * 512);
    aXl1 = *(const bf16x8*)(sm + rA + 8192 + 1 * 512);

    for (int t = 0; t < 32; ++t) {
        const u16* smr = sm + ((t & 1) ? 32768u : 0u);
        u16*       smw = sm + ((t & 1) ? 0u : 32768u);
        const int  kn  = (t + 1) * 32;   // tile 32 staging reads slack space (safe, never consumed)
        // ---- phase 0 (uses set X; tail loads Y <- phase1 frags of tile t)
        gld_lds16(gsrc[0] + kn, smw + ldst[0]);
        gld_lds16(gsrc[1] + kn, smw + ldst[1]);
        gld_lds16(gsrc[2] + kn, smw + ldst[2]);
        asm volatile("s_waitcnt vmcnt(5)" ::: "memory");
        asm volatile("s_barrier" ::: "memory");
        __builtin_amdgcn_sched_barrier(0);
        __builtin_amdgcn_s_setprio(1);
        MFROW(0, aXh0, bh) MFROW(1, aXh1, bh)
        MFROW(0, aXl0, bh) MFROW(1, aXl1, bh)
        MFROW(0, aXh0, bl) MFROW(1, aXh1, bl)
        __builtin_amdgcn_s_setprio(0);
        __builtin_amdgcn_sched_barrier(0);
        aYh0 = *(const bf16x8*)(smr + rA + 2 * 512);
        aYh1 = *(const bf16x8*)(smr + rA + 3 * 512);
        aYl0 = *(const bf16x8*)(smr + rA + 8192 + 2 * 512);
        aYl1 = *(const bf16x8*)(smr + rA + 8192 + 3 * 512);
        // ---- phase 1 (uses Y; tail loads X <- phase2 frags)
        gld_lds16(gsrc[3] + kn, smw + ldst[3]);
        gld_lds16(gsrc[4] + kn, smw + ldst[4]);
        asm volatile("s_waitcnt vmcnt(6)" ::: "memory");
        asm volatile("s_barrier" ::: "memory");
        __builtin_amdgcn_sched_barrier(0);
        __builtin_amdgcn_s_setprio(1);
        MFROW(2, aYh0, bh) MFROW(3, aYh1, bh)
        MFROW(2, aYl0, bh) MFROW(3, aYl1, bh)
        MFROW(2, aYh0, bl) MFROW(3, aYh1, bl)
        __builtin_amdgcn_s_setprio(0);
        __builtin_amdgcn_sched_barrier(0);
        aXh0 = *(const bf16x8*)(smr + rA + 4 * 512);
        aXh1 = *(const bf16x8*)(smr + rA + 5 * 512);
        aXl0 = *(const bf16x8*)(smr + rA + 8192 + 4 * 512);
        aXl1 = *(const bf16x8*)(smr + rA + 8192 + 5 * 512);
        // ---- phase 2 (uses X; tail loads Y <- phase3 frags)
        gld_lds16(gsrc[5] + kn, smw + ldst[5]);
        gld_lds16(gsrc[6] + kn, smw + ldst[6]);
        asm volatile("s_waitcnt vmcnt(7)" ::: "memory");
        asm volatile("s_barrier" ::: "memory");
        __builtin_amdgcn_sched_barrier(0);
        __builtin_amdgcn_s_setprio(1);
        MFROW(4, aXh0, bh) MFROW(5, aXh1, bh)
        MFROW(4, aXl0, bh) MFROW(5, aXl1, bh)
        MFROW(4, aXh0, bl) MFROW(5, aXh1, bl)
        __builtin_amdgcn_s_setprio(0);
        __builtin_amdgcn_sched_barrier(0);
        aYh0 = *(const bf16x8*)(smr + rA + 6 * 512);
        aYh1 = *(const bf16x8*)(smr + rA + 7 * 512);
        aYl0 = *(const bf16x8*)(smr + rA + 8192 + 6 * 512);
        aYl1 = *(const bf16x8*)(smr + rA + 8192 + 7 * 512);
        // ---- phase 3 (uses Y; tail loads X + B <- tile t+1 from smw)
        gld_lds16(gsrc[7] + kn, smw + ldst[7]);
        asm volatile("s_waitcnt vmcnt(3)" ::: "memory");   // t+1:c0..c4 landed
        asm volatile("s_barrier" ::: "memory");
        __builtin_amdgcn_sched_barrier(0);
        __builtin_amdgcn_s_setprio(1);
        MFROW(6, aYh0, bh) MFROW(7, aYh1, bh)
        MFROW(6, aYl0, bh) MFROW(7, aYl1, bh)
        MFROW(6, aYh0, bl) MFROW(7, aYh1, bl)
        __builtin_amdgcn_s_setprio(0);
        __builtin_amdgcn_sched_barrier(0);
        aXh0 = *(const bf16x8*)(smw + rA + 0 * 512);
        aXh1 = *(const bf16x8*)(smw + rA + 1 * 512);
        aXl0 = *(const bf16x8*)(smw + rA + 8192 + 0 * 512);
        aXl1 = *(const bf16x8*)(smw + rA + 8192 + 1 * 512);
#pragma unroll
        for (int fn = 0; fn < 4; ++fn) {
            bh[fn] = *(const bf16x8*)(smw + rB + fn * 512);
            bl[fn] = *(const bf16x8*)(smw + rB + 8192 + fn * 512);
        }
        asm volatile("s_barrier" ::: "memory");   // bar2: iteration boundary (buffer swap)
    }

    // fused L3: per row, partial dot over this wave's 64-col window
    const int slot = bx * 4 + wn;   // 0..15, window cols = slot*64 (same as before)
#pragma unroll
    for (int fm = 0; fm < 8; ++fm) {
#pragma unroll
        for (int r = 0; r < 4; ++r) {
            int grow = bm + wm * 128 + fm * 16 + q8 * 4 + r;
            float l0 = 0.f, l1 = 0.f, l2 = 0.f;
#pragma unroll
            for (int fn = 0; fn < 4; ++fn) {
                int gcol = bn + wn * 64 + fn * 16 + tl;
                float v = fmaxf(acc[fm][fn][r] + bs2[gcol], 0.f);
                const float* w3 = Ws3 + gcol * 3;
                l0 = fmaf(v, w3[0], l0);
                l1 = fmaf(v, w3[1], l1);
                l2 = fmaf(v, w3[2], l2);
            }
#pragma unroll
            for (int off = 8; off > 0; off >>= 1) {
                l0 += __shfl_down(l0, off, 16);
                l1 += __shfl_down(l1, off, 16);
                l2 += __shfl_down(l2, off, 16);
            }
            if (tl == 0 && grow < M) {
                float* dst = part + ((size_t)grow * 16 + slot) * 3;
                dst[0] = l0; dst[1] = l1; dst[2] = l2;
            }
        }
    }
    asm volatile("s_waitcnt vmcnt(0)" ::: "memory");   // drain tail staging before exit
}

// ---------------------------------------------------------------------------
// Gathered pair layer-1, split-K over p: TO2[p][r] = xh[toks[r + p*1024]]@B(p)
// dbuf + counted vmcnt(2) (no per-K-step drain).
// ---------------------------------------------------------------------------
__global__ __launch_bounds__(256) void k_pairL1(
    const u16* __restrict__ xh, const u16* __restrict__ Wp1T4,
    float* __restrict__ TO2, const int* __restrict__ toks)
{
    __shared__ __align__(16) u16 sm[2 * 4096];      // dbuf x (A 4KB | B 4KB)
    const int tid = threadIdx.x;
    const int bid = blockIdx.x;
    const int p = bid >> 8;                  // 0/1
    const int bx = bid & 15, by = (bid >> 4) & 15;
    const int bm = by * 64, bn = bx * 64;
    const int wave = tid >> 6, lane = tid & 63;
    const int wr = wave >> 1, wc = wave & 1;
    const int q = lane >> 4, tl = lane & 15;
    const bool isO = bm >= 512;

    f32x4 zero = {0.f, 0.f, 0.f, 0.f};
    f32x4 acc[2][2];
#pragma unroll
    for (int i = 0; i < 2; ++i)
#pragma unroll
        for (int j = 0; j < 2; ++j) acc[i][j] = zero;

    const int srow = tid >> 2;
    const int scol = (tid & 3) * 8;
    const u32 oA = wave * 512;
    const u32 oB = 2048 + wave * 512;

    int arow = toks[bm + srow + p * 1024];    // per-lane row gather
    const u16* gA = xh + (size_t)arow * DIM + scol;
    const u16* gB = Wp1T4 + ((size_t)((isO ? 2 : 0) + p) * 1024 + bn + srow) * DIM + scol;

    // prologue: tile 0 -> buf 0
    gld_lds16(gA, sm + oA);
    gld_lds16(gB, sm + oB);
    asm volatile("s_waitcnt vmcnt(0)" ::: "memory");
    asm volatile("s_barrier" ::: "memory");

    const int NT = DIM / 32;   // 24
    for (int kt = 0; kt < NT; ++kt) {
        const u16* smr = sm + ((kt & 1) ? 4096u : 0u);
        u16*       smw = sm + ((kt & 1) ? 0u : 4096u);
        if (kt < NT - 1) {
            const int k0 = (kt + 1) * 32;
            gld_lds16(gA + k0, smw + oA);
            gld_lds16(gB + k0, smw + oB);
            asm volatile("s_waitcnt vmcnt(2)" ::: "memory");
        } else {
            asm volatile("s_waitcnt vmcnt(0)" ::: "memory");
        }
        asm volatile("s_barrier" ::: "memory");
        bf16x8 af[2], bf[2];
#pragma unroll
        for (int t = 0; t < 2; ++t) {
            af[t] = *(const bf16x8*)(smr + (wr*32 + t*16 + tl) * 32 + q*8);
            bf[t] = *(const bf16x8*)(smr + 2048 + (wc*32 + t*16 + tl) * 32 + q*8);
        }
#pragma unroll
        for (int ti = 0; ti < 2; ++ti)
#pragma unroll
            for (int tj = 0; tj < 2; ++tj)
                acc[ti][tj] = __builtin_amdgcn_mfma_f32_16x16x32_bf16(af[ti], bf[tj], acc[ti][tj], 0, 0, 0);
        asm volatile("s_barrier" ::: "memory");
    }
    float* dstb = TO2 + (size_t)p * 1024 * HID;
#pragma unroll
    for (int ti = 0; ti < 2; ++ti) {
#pragma unroll
        for (int tj = 0; tj < 2; ++tj) {
            int gcol = bn + wc*32 + tj*16 + tl;
#pragma unroll
            for (int r = 0; r < 4; ++r) {
                int grow = bm + wr*32 + ti*16 + q*4 + r;
                dstb[(size_t)grow * HID + gcol] = acc[ti][tj][r];
            }
        }
    }
}

// h1s = relu(XALL[b,start,0:1024] + XALL[b,end-1,1024:2048] + wtabS[w-1]) -> split bf16
__global__ __launch_bounds__(256) void k_build_h1s(
    const float* __restrict__ XALL, const float* __restrict__ wtabS,
    u16* __restrict__ h1h, u16* __restrict__ h1l)
{
    int r = blockIdx.x;                 // 0..16159
    int b = r / NSPAN, s = r - b * NSPAN;
    int st, en, w; span_decode(s, st, en, w);
    const float4* xs = (const float4*)(XALL + (size_t)(b*SEQ + st) * 2048);
    const float4* xe = (const float4*)(XALL + (size_t)(b*SEQ + en - 1) * 2048 + 1024);
    const float4* wt = (const float4*)(wtabS + (size_t)(w-1) * HID);
    int t = threadIdx.x;
    float4 a = xs[t], bz = xe[t], c = wt[t];
    float v0 = fmaxf(a.x + bz.x + c.x, 0.f);
    float v1 = fmaxf(a.y + bz.y + c.y, 0.f);
    float v2 = fmaxf(a.z + bz.z + c.z, 0.f);
    float v3 = fmaxf(a.w + bz.w + c.w, 0.f);
    u16 h0,l0,h1,l1,h2,l2,h3,l3;
    splitbf(v0,h0,l0); splitbf(v1,h1,l1); splitbf(v2,h2,l2); splitbf(v3,h3,l3);
    size_t base = (size_t)r * HID + t * 4;
    *(uint2*)(h1h + base) = make_uint2((u32)h0 | ((u32)h1 << 16), (u32)h2 | ((u32)h3 << 16));
    *(uint2*)(h1l + base) = make_uint2((u32)l0 | ((u32)l1 << 16), (u32)l2 | ((u32)l3 << 16));
}

// ---------------------------------------------------------------------------
// k_topk (fused with span reduce+softmax): reduces partS (fixed order), writes
// out[], packs keys, bitonic-sorts 2048 u64 keys, emits top-64 + token maps.
// 1024 threads: same compare-exchange network (bit-exact), 2 iters/step.
// ---------------------------------------------------------------------------
__global__ __launch_bounds__(1024) void k_topk(
    const float* __restrict__ partS, const float* __restrict__ bs3,
    float* __restrict__ out, int* __restrict__ t_idx, int* __restrict__ o_idx,
    int* __restrict__ toks)
{
    int b = blockIdx.x >> 1;
    int head = 1 + (blockIdx.x & 1);
    int* outp = (head == 1 ? t_idx : o_idx) + b * NZ;
    __shared__ u64 keys[2048];
    int tid = threadIdx.x;
#pragma unroll
    for (int ii = 0; ii < 2; ++ii) {
        int s = tid + ii * 1024;          // 0..2047
        u32 fb = 0;
        if (s < NSPAN) {
            const float* p = partS + (size_t)(b * NSPAN + s) * 48;
            float s0 = bs3[0], s1 = bs3[1], s2 = bs3[2];
#pragma unroll
            for (int t = 0; t < 16; ++t) {
                s0 += p[t*3]; s1 += p[t*3+1]; s2 += p[t*3+2];
            }
            float m = fmaxf(s0, fmaxf(s1, s2));
            float e0 = expf(s0 - m), e1 = expf(s1 - m), e2 = expf(s2 - m);
            float inv = 1.f / (e0 + e1 + e2);
            float p0 = e0 * inv, p1 = e1 * inv, p2 = e2 * inv;
            float* o = out + (size_t)(b * NSPAN + s) * 3;
            o[0] = p0; o[1] = p1; o[2] = p2;
            union { float f; u32 u; } x;
            x.f = (head == 1) ? p1 : p2;
            fb = x.u;
        }
        keys[s] = ((u64)fb << 32) | (u64)(0xFFFFFFFFu - (u32)s);
    }
    __syncthreads();
    for (int k = 2; k <= 2048; k <<= 1) {
        for (int j = k >> 1; j > 0; j >>= 1) {
#pragma unroll
            for (int ii = 0; ii < 2; ++ii) {
                int i = tid + ii * 1024;
                int ixj = i ^ j;
                if (ixj > i) {
                    u64 a = keys[i], c = keys[ixj];
                    bool desc = (i & k) == 0;
                    bool wrong = desc ? (a < c) : (a > c);
                    if (wrong) { keys[i] = c; keys[ixj] = a; }
                }
            }
            __syncthreads();
        }
    }
    if (tid < NZ) {
        u64 key = keys[tid];
        int fi = (int)(0xFFFFFFFFu - (u32)(key & 0xFFFFFFFFu));
        if (fi < 0 || fi >= NSPAN) fi = 0;   // paranoia
        outp[tid] = fi;
        int st, en, w; span_decode(fi, st, en, w);
        int base = (head == 1 ? 0 : 512) + b * NZ + tid;
        toks[base] = b * SEQ + st;
        toks[1024 + base] = b * SEQ + en - 1;
    }
}

// ---------------------------------------------------------------------------
// k_build_h1p v2 (LDS-tiled): one block per (b, 8 i's, 4 j's) -> 32 rows.
// ---------------------------------------------------------------------------
__global__ __launch_bounds__(256) void k_build_h1p(
    const float* __restrict__ TO2, const int* __restrict__ t_idx, const int* __restrict__ o_idx,
    const float* __restrict__ wtabPt, const float* __restrict__ wtabPo,
    const float* __restrict__ dtab, u16* __restrict__ h1p)
{
    __shared__ float Ts[8][HID];    // 32 KB
    __shared__ float Os[4][HID];    // 16 KB
    const int bid = blockIdx.x;     // 1024 = 8 b x 8 it x 16 jt
    const int b = bid >> 7;
    const int it = (bid >> 4) & 7;
    const int jt = bid & 15;
    const int i0 = it * 8, j0 = jt * 4;
    const int tid = threadIdx.x;
    const int k4 = tid * 4;
    const size_t PS = (size_t)1024 * HID;

    int tinfo[8][2];                // (ta, tb) per i
    int oinfo[4][2];                // (oc, od) per j
#pragma unroll
    for (int r = 0; r < 8; ++r) {
        int i = i0 + r;
        int ts = t_idx[b*64 + i];
        int ta, tb, wt; span_decode(ts, ta, tb, wt);
        tinfo[r][0] = ta; tinfo[r][1] = tb;
        float4 t0 = *(const float4*)(TO2 + (size_t)(b*64 + i) * HID + k4);
        float4 t1 = *(const float4*)(TO2 + PS + (size_t)(b*64 + i) * HID + k4);
        float4 pp = *(const float4*)(wtabPt + (size_t)(wt-1) * HID + k4);
        Ts[r][k4+0] = t0.x + t1.x + pp.x;
        Ts[r][k4+1] = t0.y + t1.y + pp.y;
        Ts[r][k4+2] = t0.z + t1.z + pp.z;
        Ts[r][k4+3] = t0.w + t1.w + pp.w;
    }
#pragma unroll
    for (int r = 0; r < 4; ++r) {
        int j = j0 + r;
        int os = o_idx[b*64 + j];
        int oc, od, wo; span_decode(os, oc, od, wo);
        oinfo[r][0] = oc; oinfo[r][1] = od;
        float4 o0 = *(const float4*)(TO2 + (size_t)(512 + b*64 + j) * HID + k4);
        float4 o1 = *(const float4*)(TO2 + PS + (size_t)(512 + b*64 + j) * HID + k4);
        float4 qq = *(const float4*)(wtabPo + (size_t)(wo-1) * HID + k4);
        Os[r][k4+0] = o0.x + o1.x + qq.x;
        Os[r][k4+1] = o0.y + o1.y + qq.y;
        Os[r][k4+2] = o0.z + o1.z + qq.z;
        Os[r][k4+3] = o0.w + o1.w + qq.w;
    }
    __syncthreads();

#pragma unroll
    for (int ri = 0; ri < 8; ++ri) {
#pragma unroll
        for (int rj = 0; rj < 4; ++rj) {
            int ta = tinfo[ri][0], tb = tinfo[ri][1];
            int oc = oinfo[rj][0], od = oinfo[rj][1];
            int d1 = tb - oc; d1 = d1 < 0 ? -d1 : d1;
            int d2 = ta - od; d2 = d2 < 0 ? -d2 : d2;
            int dist = d1 < d2 ? d1 : d2;
            int db = dbucket(dist);
            const float4 dd = *(const float4*)(dtab + (size_t)db * HID + k4);
            float vx = fmaxf(Ts[ri][k4+0] + Os[rj][k4+0] + dd.x, 0.f);
            float vy = fmaxf(Ts[ri][k4+1] + Os[rj][k4+1] + dd.y, 0.f);
            float vz = fmaxf(Ts[ri][k4+2] + Os[rj][k4+2] + dd.z, 0.f);
            float vw = fmaxf(Ts[ri][k4+3] + Os[rj][k4+3] + dd.w, 0.f);
            u32 p0 = (u32)f2bf(vx) | ((u32)f2bf(vy) << 16);
            u32 p1 = (u32)f2bf(vz) | ((u32)f2bf(vw) << 16);
            int row = b * 4096 + (i0 + ri) * 64 + (j0 + rj);
            *(uint2*)(h1p + (size_t)row * HID + k4) = make_uint2(p0, p1);
        }
    }
}

// ---------------------------------------------------------------------------
// Pair layer-2 GEMM v3.2 (R4 proven form): 256x256 tile, 8 waves, BK=64, dbuf,
// 4 phases x 16 MFMA, two barriers/phase. Chunks c0..c3=B, c4+p=A group p.
// Issue order 3/2/2/1 with waits {5,6,7,3}. Per-acc k-order: tiles ascending,
// ks0,ks1 (bit-identical). Fused layer-3 epilogue, 16 slots.
// ---------------------------------------------------------------------------
#define PAIR_PHASE(P, VMC, GLDS) \
    { \
        bf16x8 a00 = *(const bf16x8*)(smr + rA + ((2*(P)+0)*2+0)*512); \
        bf16x8 a01 = *(const bf16x8*)(smr + rA + ((2*(P)+0)*2+1)*512); \
        bf16x8 a10 = *(const bf16x8*)(smr + rA + ((2*(P)+1)*2+0)*512); \
        bf16x8 a11 = *(const bf16x8*)(smr + rA + ((2*(P)+1)*2+1)*512); \
        if ((P) == 0) { \
            b0[0] = *(const bf16x8*)(smr + rB + 0*512); \
            b1[0] = *(const bf16x8*)(smr + rB + 1*512); \
            b0[1] = *(const bf16x8*)(smr + rB + 2*512); \
            b1[1] = *(const bf16x8*)(smr + rB + 3*512); \
            b0[2] = *(const bf16x8*)(smr + rB + 4*512); \
            b1[2] = *(const bf16x8*)(smr + rB + 5*512); \
            b0[3] = *(const bf16x8*)(smr + rB + 6*512); \
            b1[3] = *(const bf16x8*)(smr + rB + 7*512); \
        } \
        GLDS \
        asm volatile("s_waitcnt vmcnt(" #VMC ")" ::: "memory"); \
        asm volatile("s_barrier" ::: "memory"); \
        __builtin_amdgcn_sched_barrier(0); \
        __builtin_amdgcn_s_setprio(1); \
        MFROW(2*(P)+0, a00, b0) \
        MFROW(2*(P)+1, a10, b0) \
        MFROW(2*(P)+0, a01, b1) \
        MFROW(2*(P)+1, a11, b1) \
        __builtin_amdgcn_s_setprio(0); \
        asm volatile("s_barrier" ::: "memory"); \
    }

__global__ __launch_bounds__(512, 2) void k_pair_l2(
    const u16* __restrict__ Abf, const u16* __restrict__ BT,
    const float* __restrict__ bp2, const float* __restrict__ Wp3,
    float* __restrict__ part)
{
    __shared__ __align__(16) u16 sm[65536];            // 128 KiB, 2 bufs
    const int tid = threadIdx.x;
    const int swz = (blockIdx.x & 7) * 64 + (blockIdx.x >> 3);   // 512 wgs, 8 XCDs
    const int by = swz >> 2, bx = swz & 3;
    const int bm = by * 256, bn = bx * 256;
    const int wave = tid >> 6, lane = tid & 63;
    const int wm = wave >> 2, wn = wave & 3;
    const int tl = lane & 15, q8 = lane >> 4;

    const int sr  = lane >> 2;
    const int scs = lane & 3;
    const int scl = scs ^ ((sr >> 1) & 3);
    // chunk table: c0..c3 = B (half0 sb=w, half0 sb=8+w, half1 sb=w, half1 sb=8+w),
    // c4+p = A group p (half=w>>2, sb=4p+(w&3));  sb = rowsub*2 + ks
    const u16* gsrc[8];
    u32 ldst[8];
#pragma unroll
    for (int c = 0; c < 4; ++c) {
        int half = c >> 1;
        int sb   = (c & 1) * 8 + wave;
        int row  = bn + half * 128 + (sb >> 1) * 16 + sr;
        gsrc[c] = BT + (size_t)row * HID + (sb & 1) * 32 + scl * 8;
        ldst[c] = 16384 + half * 8192 + sb * 512;
    }
#pragma unroll
    for (int p = 0; p < 4; ++p) {
        int half = wave >> 2;
        int sb   = 4 * p + (wave & 3);
        int row  = bm + half * 128 + (sb >> 1) * 16 + sr;
        gsrc[4 + p] = Abf + (size_t)row * HID + (sb & 1) * 32 + scl * 8;
        ldst[4 + p] = half * 8192 + sb * 512;
    }
    const int cpr = q8 ^ ((tl >> 1) & 3);
    const u32 lof = (u32)(tl * 32 + cpr * 8);
    const u32 rA  = (u32)(wm * 8192) + lof;
    const u32 rB  = 16384u + (u32)((wn >> 1) * 8192 + (wn & 1) * 4096) + lof;

    f32x4 zero = {0.f, 0.f, 0.f, 0.f};
    f32x4 acc[8][4];
#pragma unroll
    for (int i = 0; i < 8; ++i)
#pragma unroll
        for (int j = 0; j < 4; ++j) acc[i][j] = zero;

    // prologue: tile 0 -> buf 0
#pragma unroll
    for (int c = 0; c < 8; ++c) gld_lds16(gsrc[c], sm + ldst[c]);
    asm volatile("s_waitcnt vmcnt(3)" ::: "memory");   // c0..c4 done
    asm volatile("s_barrier" ::: "memory");

    bf16x8 b0[4], b1[4];
    for (int t = 0; t < 16; ++t) {
        const u16* smr = sm + ((t & 1) ? 32768u : 0u);
        u16*       smw = sm + ((t & 1) ? 0u : 32768u);
        const int  kn  = (t + 1) * 64;   // tile 16 staging reads slack space (safe, never consumed)
        PAIR_PHASE(0, 5,
            gld_lds16(gsrc[0] + kn, smw + ldst[0]);
            gld_lds16(gsrc[1] + kn, smw + ldst[1]);
            gld_lds16(gsrc[2] + kn, smw + ldst[2]);)
        PAIR_PHASE(1, 6,
            gld_lds16(gsrc[3] + kn, smw + ldst[3]);
            gld_lds16(gsrc[4] + kn, smw + ldst[4]);)
        PAIR_PHASE(2, 7,
            gld_lds16(gsrc[5] + kn, smw + ldst[5]);
            gld_lds16(gsrc[6] + kn, smw + ldst[6]);)
        PAIR_PHASE(3, 3,
            gld_lds16(gsrc[7] + kn, smw + ldst[7]);)
    }

    // fused L3 projection
    const int slot = bx * 4 + wn;   // window cols = slot*64 (same as before)
#pragma unroll
    for (int fm = 0; fm < 8; ++fm) {
#pragma unroll
        for (int r = 0; r < 4; ++r) {
            int grow = bm + wm * 128 + fm * 16 + q8 * 4 + r;
            float l0 = 0.f, l1 = 0.f, l2 = 0.f, l3 = 0.f;
#pragma unroll
            for (int fn = 0; fn < 4; ++fn) {
                int gcol = bn + wn * 64 + fn * 16 + tl;
                float v = fmaxf(acc[fm][fn][r] + bp2[gcol], 0.f);
                const float4 w = *(const float4*)(Wp3 + gcol * 4);
                l0 = fmaf(v, w.x, l0); l1 = fmaf(v, w.y, l1);
                l2 = fmaf(v, w.z, l2); l3 = fmaf(v, w.w, l3);
            }
#pragma unroll
            for (int off = 8; off > 0; off >>= 1) {
                l0 += __shfl_down(l0, off, 16);
                l1 += __shfl_down(l1, off, 16);
                l2 += __shfl_down(l2, off, 16);
                l3 += __shfl_down(l3, off, 16);
            }
            if (tl == 0) {
                float* dst = part + ((size_t)grow * 16 + slot) * 4;
                dst[0] = l0; dst[1] = l1; dst[2] = l2; dst[3] = l3;
            }
        }
    }
    asm volatile("s_waitcnt vmcnt(0)" ::: "memory");   // drain tail staging before exit
}

// reduce 16 slots (fixed order) + softmax -> out[48480 + r*4 + c]
__global__ __launch_bounds__(256) void k_pair_red(
    const float* __restrict__ part, const float* __restrict__ bp3,
    float* __restrict__ out)
{
    int r = blockIdx.x * 256 + threadIdx.x;   // 32768 = 128*256 exact
    const float4* p = (const float4*)(part + (size_t)r * 64);
    float s0 = bp3[0], s1 = bp3[1], s2 = bp3[2], s3 = bp3[3];
#pragma unroll
    for (int t = 0; t < 16; ++t) {
        float4 v = p[t];
        s0 += v.x; s1 += v.y; s2 += v.z; s3 += v.w;
    }
    float m = fmaxf(fmaxf(s0, s1), fmaxf(s2, s3));
    float e0 = expf(s0 - m), e1 = expf(s1 - m), e2 = expf(s2 - m), e3 = expf(s3 - m);
    float inv = 1.f / (e0 + e1 + e2 + e3);
    float* o = out + (size_t)r * 4;
    o[0] = e0 * inv; o[1] = e1 * inv; o[2] = e2 * inv; o[3] = e3 * inv;
}

extern "C" void kernel_launch(void* const* d_in, const int* in_sizes, int n_in,
                              void* d_out, int out_size, void* d_ws, size_t ws_size,
                              hipStream_t stream)
{
    const float* x    = (const float*)d_in[0];
    const float* wemb = (const float*)d_in[1];
    const float* demb = (const float*)d_in[2];
    const float* Ws1  = (const float*)d_in[3];
    const float* bs1  = (const float*)d_in[4];
    const float* Ws2  = (const float*)d_in[5];
    const float* bs2  = (const float*)d_in[6];
    const float* Ws3  = (const float*)d_in[7];
    const float* bs3  = (const float*)d_in[8];
    const float* Wp1  = (const float*)d_in[9];
    const float* bp1  = (const float*)d_in[10];
    const float* Wp2  = (const float*)d_in[11];
    const float* bp2  = (const float*)d_in[12];
    const float* Wp3  = (const float*)d_in[13];
    const float* bp3  = (const float*)d_in[14];
    float* out = (float*)d_out;
    char* ws = (char*)d_ws;

    // ---- workspace arena, lifetime-aliased (~162 MB) ----
    const size_t RSZ = (size_t)32768 * HID * 2;   // 64 MiB
    size_t off = 0;
    auto alloc = [&](size_t bytes) -> void* {
        void* p = ws + off;
        off += (bytes + 255) & ~(size_t)255;
        return p;
    };
    char* R1 = (char*)alloc(RSZ);
    char* R2 = (char*)alloc(RSZ);
    u16*   h1h  = (u16*)R1;                              // 33.1 MB
    u16*   h1l  = (u16*)(R1 + (size_t)16160 * HID * 2);  // 33.1 MB
    float* XALL = (float*)R2;                            // 16 MiB
    u16*   xl   = (u16*)(R2 + (16u << 20));              // 3 MB
    u16*   W1Th = (u16*)(R2 + (19u << 20));              // 3 MB
    u16*   W1Tl = (u16*)(R2 + (22u << 20));              // 3 MB
    u16*   h1p  = (u16*)R2;                              // 64 MiB (after the above dead)
    u16*   xh     = (u16*)alloc((size_t)2048 * DIM * 2);     // 3 MB PERSISTENT
    float* TO2    = (float*)alloc((size_t)2 * 1024 * HID * 4);   // 8 MB
    float* partS  = (float*)alloc((size_t)16160 * 16 * 3 * 4);   // 3.1 MB
    float* partP  = (float*)alloc((size_t)32768 * 16 * 4 * 4);   // 8.4 MB
    u16*   W2Th   = (u16*)alloc((size_t)1024 * 1024 * 2);
    u16*   W2Tl   = (u16*)alloc((size_t)1024 * 1024 * 2);
    u16*   Wp2T   = (u16*)alloc((size_t)1024 * 1024 * 2);
    u16*   Wp1T4  = (u16*)alloc((size_t)4 * 1024 * 768 * 2);
    float* wtabS  = (float*)alloc(8 * HID * 4);
    float* wtabPt = (float*)alloc(8 * HID * 4);
    float* wtabPo = (float*)alloc(8 * HID * 4);
    float* dtab   = (float*)alloc(14 * HID * 4);
    int*   t_idx  = (int*)alloc(BATCH * NZ * 4);
    int*   o_idx  = (int*)alloc(BATCH * NZ * 4);
    int*   toks   = (int*)alloc(2048 * 4);
    (void)ws_size; (void)in_sizes; (void)n_in; (void)out_size;

    // prep (fused): x split + tables + all weight transposes
    k_prep<<<12952, 256, 0, stream>>>(x, xh, xl, wemb, demb, bs1, bp1,
                                      wtabS, wtabPt, wtabPo, dtab,
                                      Ws1, W1Th, W1Tl, Ws2, W2Th, W2Tl,
                                      Wp2, Wp2T, Wp1, Wp1T4);

    // layer-1 factorization: XALL = x2d @ [Ws1_top | Ws1_mid] (3-pass split-bf16)
    // 8-wave swizzled dbuf version, 512 threads
    k_gemm3bf<<<256, 512, 0, stream>>>(xh, xl, 768, W1Th, W1Tl, 768,
                                       XALL, 2048, 2048, 768, 16, 4);
    k_build_h1s<<<16160, 256, 0, stream>>>(XALL, wtabS, h1h, h1l);
    // span layer2 + FUSED layer3 partials: reg-pipelined 4-phase counted-vmcnt (R5 form)
    k_span_l2<<<256, 512, 0, stream>>>(h1h, h1l, W2Th, W2Tl, bs2, Ws3, partS, 16160);
    // fused reduce+softmax+topk+toks (1024-thread bitonic, bit-exact network)
    k_topk<<<16, 1024, 0, stream>>>(partS, bs3, out, t_idx, o_idx, toks);
    // gathered pair layer-1: split-K bf16 MFMA, dbuf counted-vmcnt
    k_pairL1<<<512, 256, 0, stream>>>(xh, Wp1T4, TO2, toks);
    // h1p build: LDS-tiled (8i x 4j per block), 1024 blocks
    k_build_h1p<<<1024, 256, 0, stream>>>(TO2, t_idx, o_idx, wtabPt, wtabPo, dtab, h1p);
    // pair layer2 + FUSED layer3 partials: 4-phase counted-vmcnt (R4 form)
    k_pair_l2<<<512, 512, 0, stream>>>(h1p, Wp2T, bp2, Wp3, partP);
    k_pair_red<<<128, 256, 0, stream>>>(partP, bp3, out + 48480);
}